// Round 3
// baseline (391.668 us; speedup 1.0000x reference)
//
#include <hip/hip_runtime.h>
#include <cstdint>
#include <math.h>

// Problem constants (from reference)
#define GRID_W 96
#define GRID_L 96
#define GRID_H 48
#define NVOX (GRID_W * GRID_L * GRID_H)   // 442368
#define VOXEL_SIZE 0.05f
#define MIN_PTS 10
#define BATCH 4
#define CHANS 16
#define NPTS (480 * 640)                  // 307200 points per batch
#define TOTPTS (BATCH * NPTS)             // 1228800
#define TOTVOX (BATCH * NVOX)             // 1769472

// Scan geometry: 864 blocks x 256 threads x 8 elems = 1769472 exactly.
#define SCAN_BLKS 864
#define SCAN_TPB 256
#define SCAN_EPT 8
#define SCAN_CHUNK (SCAN_TPB * SCAN_EPT)  // 2048

// ---- workspace layout (bytes) ----
#define WS_CNT     0
#define WS_OFFSETS (WS_CNT + TOTVOX * 4)       //  7,077,888
#define WS_VIDX    (WS_OFFSETS + TOTVOX * 4)   // 14,155,776
#define WS_RANK    (WS_VIDX + TOTPTS * 4)      // 19,070,976
#define WS_IDS     (WS_RANK + TOTPTS * 4)      // 23,986,176
#define WS_SUMS    (WS_IDS + TOTPTS * 4)       // 28,901,376
#define WS_NEEDED  ((size_t)(WS_SUMS + 4096))  // ~28.9 MB

// ============================== fast path ==============================

__global__ void k_zero_cnt(uint4* __restrict__ cnt4) {
    int i = blockIdx.x * blockDim.x + threadIdx.x;
    if (i < TOTVOX / 4) cnt4[i] = uint4{0u, 0u, 0u, 0u};
}

// Per-point voxel id + histogram. The atomic's return value is the point's
// rank within its voxel -> later scatter needs no atomics at all.
__global__ void k_vidx_hist(const float* __restrict__ coords,   // [B,3,NPTS]
                            const float* __restrict__ origin,   // [B,3]
                            int*         __restrict__ vidx,     // [TOTPTS]
                            unsigned*    __restrict__ rank,     // [TOTPTS]
                            unsigned*    __restrict__ cnt)      // [TOTVOX]
{
    int id = blockIdx.x * blockDim.x + threadIdx.x;
    if (id >= TOTPTS) return;
    int b = id / NPTS;
    int n = id - b * NPTS;

    const float* cb = coords + (size_t)b * 3 * NPTS;
    float x = cb[n];
    float y = cb[NPTS + n];
    float z = cb[2 * NPTS + n];
    float ox = origin[b * 3 + 0];
    float oy = origin[b * 3 + 1];
    float oz = origin[b * 3 + 2];

    // IEEE f32 division + floorf: must match numpy reference binning exactly.
    int ix = (int)floorf((x - ox) / VOXEL_SIZE);
    int iy = (int)floorf((y - oy) / VOXEL_SIZE);
    int iz = (int)floorf((z - oz) / VOXEL_SIZE);

    int v = -1;
    unsigned r = 0;
    if ((unsigned)ix < GRID_W && (unsigned)iy < GRID_L && (unsigned)iz < GRID_H) {
        v = b * NVOX + ix * (GRID_L * GRID_H) + iy * GRID_H + iz;
        r = atomicAdd(&cnt[v], 1u);
    }
    vidx[id] = v;
    rank[id] = r;
}

// Scan level 1: per-2048-chunk exclusive partials + chunk totals.
// Also emits the occupancy output plane (it reads every count anyway).
__global__ void k_scan1(const unsigned* __restrict__ cnt,
                        unsigned* __restrict__ offsets,
                        unsigned* __restrict__ sums,
                        float*    __restrict__ occ)      // [TOTVOX] in d_out
{
    __shared__ unsigned s[SCAN_TPB];
    int t = threadIdx.x;
    int base = blockIdx.x * SCAN_CHUNK + t * SCAN_EPT;

    uint4 a = ((const uint4*)(cnt + base))[0];
    uint4 c = ((const uint4*)(cnt + base))[1];
    unsigned e[SCAN_EPT] = {a.x, a.y, a.z, a.w, c.x, c.y, c.z, c.w};

    float4 oc0, oc1;
    oc0.x = (e[0] >= MIN_PTS) ? 1.f : 0.f;  oc0.y = (e[1] >= MIN_PTS) ? 1.f : 0.f;
    oc0.z = (e[2] >= MIN_PTS) ? 1.f : 0.f;  oc0.w = (e[3] >= MIN_PTS) ? 1.f : 0.f;
    oc1.x = (e[4] >= MIN_PTS) ? 1.f : 0.f;  oc1.y = (e[5] >= MIN_PTS) ? 1.f : 0.f;
    oc1.z = (e[6] >= MIN_PTS) ? 1.f : 0.f;  oc1.w = (e[7] >= MIN_PTS) ? 1.f : 0.f;
    ((float4*)(occ + base))[0] = oc0;
    ((float4*)(occ + base))[1] = oc1;

    unsigned tot = 0;
    #pragma unroll
    for (int k = 0; k < SCAN_EPT; ++k) { unsigned v = e[k]; e[k] = tot; tot += v; }

    s[t] = tot;
    __syncthreads();
    #pragma unroll
    for (int off = 1; off < SCAN_TPB; off <<= 1) {
        unsigned v = (t >= off) ? s[t - off] : 0u;
        __syncthreads();
        s[t] += v;
        __syncthreads();
    }
    unsigned prefix = s[t] - tot;   // exclusive within chunk
    #pragma unroll
    for (int k = 0; k < SCAN_EPT; ++k) e[k] += prefix;

    ((uint4*)(offsets + base))[0] = uint4{e[0], e[1], e[2], e[3]};
    ((uint4*)(offsets + base))[1] = uint4{e[4], e[5], e[6], e[7]};

    if (t == SCAN_TPB - 1) sums[blockIdx.x] = s[t];
}

// Scan level 2: exclusive scan of the 864 chunk sums (single block).
// Consumers add sums[v >> 11] themselves (no level-3 pass).
__global__ void k_scan2(unsigned* __restrict__ sums) {
    __shared__ unsigned s[1024];
    int t = threadIdx.x;
    unsigned my = (t < SCAN_BLKS) ? sums[t] : 0u;
    s[t] = my;
    __syncthreads();
    #pragma unroll
    for (int off = 1; off < 1024; off <<= 1) {
        unsigned v = (t >= off) ? s[t - off] : 0u;
        __syncthreads();
        s[t] += v;
        __syncthreads();
    }
    if (t < SCAN_BLKS) sums[t] = s[t] - my;   // exclusive
}

// Scatter each in-bounds point's index-within-batch into its voxel segment.
// No atomics: pos = chunk-local offset + chunk prefix + rank-from-histogram.
__global__ void k_scatter_ids(const int*      __restrict__ vidx,    // [TOTPTS]
                              const unsigned* __restrict__ rank,    // [TOTPTS]
                              const unsigned* __restrict__ offsets, // [TOTVOX]
                              const unsigned* __restrict__ sums,    // [SCAN_BLKS]
                              int*            __restrict__ ids)     // [TOTPTS]
{
    int id = blockIdx.x * blockDim.x + threadIdx.x;
    if (id >= TOTPTS) return;
    int v = vidx[id];
    if (v < 0) return;
    unsigned pos = offsets[v] + sums[v >> 11] + rank[id];
    int b = id / NPTS;
    ids[pos] = id - b * NPTS;   // n within batch (b recoverable from segment)
}

// Gather + finalize: one thread per output element of data (plane-major ->
// fully coalesced writes). Random 4B attr gathers stay within a 1.2 MB
// channel plane -> L2/L3 resident.
__global__ void k_gather_plane(const float*    __restrict__ attrs,   // [B,C,NPTS]
                               const int*      __restrict__ ids,     // [TOTPTS]
                               const unsigned* __restrict__ cnt,     // [TOTVOX]
                               const unsigned* __restrict__ offsets, // [TOTVOX]
                               const unsigned* __restrict__ sums,    // [SCAN_BLKS]
                               float*          __restrict__ data)    // [B,C,NVOX]
{
    int g = blockIdx.x * blockDim.x + threadIdx.x;
    if (g >= BATCH * CHANS * NVOX) return;
    int b = g / (CHANS * NVOX);
    int rem = g - b * (CHANS * NVOX);
    int c = rem / NVOX;
    int v = rem - c * NVOX;
    int vox = b * NVOX + v;

    unsigned k = cnt[vox];
    float val = 0.f;
    if (k >= MIN_PTS) {
        unsigned start = offsets[vox] + sums[vox >> 11];
        const float* plane = attrs + (size_t)(b * CHANS + c) * NPTS;
        const float ninf = -__builtin_inff();
        float m0 = ninf, m1 = ninf, m2 = ninf, m3 = ninf;
        unsigned j = 0;
        for (; j + 4 <= k; j += 4) {
            int n0 = ids[start + j + 0];
            int n1 = ids[start + j + 1];
            int n2 = ids[start + j + 2];
            int n3 = ids[start + j + 3];
            m0 = fmaxf(m0, plane[n0]);
            m1 = fmaxf(m1, plane[n1]);
            m2 = fmaxf(m2, plane[n2]);
            m3 = fmaxf(m3, plane[n3]);
        }
        for (; j < k; ++j) m0 = fmaxf(m0, plane[ids[start + j]]);
        float m = fmaxf(fmaxf(m0, m1), fmaxf(m2, m3));
        val = isfinite(m) ? m : 0.f;
    }
    data[g] = val;
}

// ============================== fallback path (round-1) ==============================

__device__ __forceinline__ unsigned flip_f32(float f) {
    unsigned u = __float_as_uint(f);
    unsigned mask = (unsigned)(-(int)(u >> 31)) | 0x80000000u;
    return u ^ mask;
}
__device__ __forceinline__ float unflip_f32(unsigned u) {
    unsigned mask = ((u >> 31) - 1u) | 0x80000000u;
    return __uint_as_float(u ^ mask);
}
#define FLIP_NEG_INF 0x007FFFFFu

__global__ void pv_init(uint4* __restrict__ out) {
    const int DATA4 = BATCH * CHANS * NVOX / 4;
    const int TOT4  = BATCH * (CHANS + 1) * NVOX / 4;
    int i = blockIdx.x * blockDim.x + threadIdx.x;
    if (i < TOT4) {
        unsigned val = (i < DATA4) ? FLIP_NEG_INF : 0u;
        out[i] = uint4{val, val, val, val};
    }
}

__global__ void pv_scatter(const float* __restrict__ coords,
                           const float* __restrict__ attrs,
                           const float* __restrict__ origin,
                           unsigned*    __restrict__ data_u,
                           unsigned*    __restrict__ cnt)
{
    int id = blockIdx.x * blockDim.x + threadIdx.x;
    if (id >= TOTPTS) return;
    int b = id / NPTS;
    int n = id - b * NPTS;
    const float* cb = coords + (size_t)b * 3 * NPTS;
    float x = cb[n], y = cb[NPTS + n], z = cb[2 * NPTS + n];
    float ox = origin[b * 3 + 0], oy = origin[b * 3 + 1], oz = origin[b * 3 + 2];
    int ix = (int)floorf((x - ox) / VOXEL_SIZE);
    int iy = (int)floorf((y - oy) / VOXEL_SIZE);
    int iz = (int)floorf((z - oz) / VOXEL_SIZE);
    if ((unsigned)ix < GRID_W && (unsigned)iy < GRID_L && (unsigned)iz < GRID_H) {
        int flat = ix * (GRID_L * GRID_H) + iy * GRID_H + iz;
        atomicAdd(&cnt[b * NVOX + flat], 1u);
        const float* ab = attrs + (size_t)b * CHANS * NPTS + n;
        unsigned*    db = data_u + (size_t)b * CHANS * NVOX + flat;
        #pragma unroll
        for (int c = 0; c < CHANS; ++c)
            atomicMax(&db[(size_t)c * NVOX], flip_f32(ab[(size_t)c * NPTS]));
    }
}

__global__ void pv_finalize(unsigned* __restrict__ data_u,
                            unsigned* __restrict__ cnt_u)
{
    int id = blockIdx.x * blockDim.x + threadIdx.x;
    if (id >= TOTVOX) return;
    int b = id / NVOX;
    int v = id - b * NVOX;
    unsigned cnt = cnt_u[id];
    bool occ = (cnt >= MIN_PTS);
    ((float*)cnt_u)[id] = occ ? 1.0f : 0.0f;
    unsigned* db = data_u + (size_t)b * CHANS * NVOX + v;
    #pragma unroll
    for (int c = 0; c < CHANS; ++c) {
        float f = unflip_f32(db[(size_t)c * NVOX]);
        ((float*)db)[(size_t)c * NVOX] = (occ && isfinite(f)) ? f : 0.0f;
    }
}

// ============================== launch ==============================

extern "C" void kernel_launch(void* const* d_in, const int* in_sizes, int n_in,
                              void* d_out, int out_size, void* d_ws, size_t ws_size,
                              hipStream_t stream) {
    const float* coords = (const float*)d_in[0];  // [4,3,480,640]
    const float* attrs  = (const float*)d_in[1];  // [4,16,480,640]
    const float* origin = (const float*)d_in[2];  // [4,3]

    float* out = (float*)d_out;
    float* data = out;                                          // [B,C,NVOX]
    float* occ  = out + (size_t)BATCH * CHANS * NVOX;           // [B,NVOX]

    if (ws_size >= WS_NEEDED) {
        char* ws = (char*)d_ws;
        unsigned* cnt     = (unsigned*)(ws + WS_CNT);
        unsigned* offsets = (unsigned*)(ws + WS_OFFSETS);
        int*      vidx    = (int*)(ws + WS_VIDX);
        unsigned* rank    = (unsigned*)(ws + WS_RANK);
        int*      ids     = (int*)(ws + WS_IDS);
        unsigned* sums    = (unsigned*)(ws + WS_SUMS);

        k_zero_cnt<<<(TOTVOX / 4 + 255) / 256, 256, 0, stream>>>((uint4*)cnt);
        k_vidx_hist<<<(TOTPTS + 255) / 256, 256, 0, stream>>>(coords, origin, vidx, rank, cnt);
        k_scan1<<<SCAN_BLKS, SCAN_TPB, 0, stream>>>(cnt, offsets, sums, occ);
        k_scan2<<<1, 1024, 0, stream>>>(sums);
        k_scatter_ids<<<(TOTPTS + 255) / 256, 256, 0, stream>>>(vidx, rank, offsets, sums, ids);
        const int NG = BATCH * CHANS * NVOX;
        k_gather_plane<<<(NG + 255) / 256, 256, 0, stream>>>(attrs, ids, cnt, offsets, sums, data);
    } else {
        unsigned* data_u = (unsigned*)data;
        unsigned* cnt    = (unsigned*)occ;
        const int TOT4 = BATCH * (CHANS + 1) * NVOX / 4;
        pv_init<<<(TOT4 + 255) / 256, 256, 0, stream>>>((uint4*)d_out);
        pv_scatter<<<(TOTPTS + 255) / 256, 256, 0, stream>>>(coords, attrs, origin, data_u, cnt);
        pv_finalize<<<(TOTVOX + 255) / 256, 256, 0, stream>>>(data_u, cnt);
    }
}

// Round 4
// 389.501 us; speedup vs baseline: 1.0056x; 1.0056x over previous
//
#include <hip/hip_runtime.h>
#include <cstdint>
#include <math.h>

// Problem constants (from reference)
#define GRID_W 96
#define GRID_L 96
#define GRID_H 48
#define NVOX (GRID_W * GRID_L * GRID_H)   // 442368
#define VOXEL_SIZE 0.05f
#define MIN_PTS 10
#define BATCH 4
#define CHANS 16
#define NPTS (480 * 640)                  // 307200 points per batch
#define TOTPTS (BATCH * NPTS)             // 1228800
#define TOTVOX (BATCH * NVOX)             // 1769472

// Scan geometry: 864 blocks x 256 threads x 8 elems = 1769472 exactly.
#define SCAN_BLKS 864
#define SCAN_TPB 256
#define SCAN_EPT 8
#define SCAN_CHUNK (SCAN_TPB * SCAN_EPT)  // 2048

// Gather geometry
#define GBLK_PER_PLANE (NVOX / 256)       // 1728 blocks of 256 per plane-group
#define NGROUPS 16                        // 4 batches x 4 channel-quads
#define GATHER_BLKS (NGROUPS * GBLK_PER_PLANE)  // 27648

// ---- workspace layout (bytes) ----
#define WS_CNT     0
#define WS_OFFSETS (WS_CNT + TOTVOX * 4)            //  7,077,888
#define WS_VIDX    (WS_OFFSETS + (TOTVOX + 4) * 4)  // 14,155,792+
#define WS_RANK    (WS_VIDX + TOTPTS * 4)
#define WS_IDS     (WS_RANK + TOTPTS * 4)
#define WS_SUMS    (WS_IDS + TOTPTS * 4)
#define WS_NEEDED  ((size_t)(WS_SUMS + 8192))       // ~28.9 MB

// ============================== fast path ==============================

__global__ void k_zero_cnt(uint4* __restrict__ cnt4, unsigned* __restrict__ offsets) {
    int i = blockIdx.x * blockDim.x + threadIdx.x;
    if (i < TOTVOX / 4) cnt4[i] = uint4{0u, 0u, 0u, 0u};
    if (i == 0) offsets[TOTVOX] = 0u;   // sentinel for k = start(v+1)-start(v)
}

// Per-point voxel id + histogram, 4 points/thread with float4 coord loads.
// The atomic's return value is the point's rank within its voxel -> later
// scatter needs no atomics at all.
__global__ void k_vidx_hist4(const float* __restrict__ coords,   // [B,3,NPTS]
                             const float* __restrict__ origin,   // [B,3]
                             int*         __restrict__ vidx,     // [TOTPTS]
                             unsigned*    __restrict__ rank,     // [TOTPTS]
                             unsigned*    __restrict__ cnt)      // [TOTVOX]
{
    int t = blockIdx.x * blockDim.x + threadIdx.x;
    if (t >= TOTPTS / 4) return;
    int pid = t * 4;
    int b = pid / NPTS;          // NPTS % 4 == 0 -> all 4 points same batch
    int n = pid - b * NPTS;

    const float* cb = coords + (size_t)b * 3 * NPTS;
    float4 X = *(const float4*)(cb + n);
    float4 Y = *(const float4*)(cb + NPTS + n);
    float4 Z = *(const float4*)(cb + 2 * NPTS + n);
    float ox = origin[b * 3 + 0];
    float oy = origin[b * 3 + 1];
    float oz = origin[b * 3 + 2];

    float xs[4] = {X.x, X.y, X.z, X.w};
    float ys[4] = {Y.x, Y.y, Y.z, Y.w};
    float zs[4] = {Z.x, Z.y, Z.z, Z.w};
    int vs[4]; unsigned rs[4];
    #pragma unroll
    for (int k = 0; k < 4; ++k) {
        // IEEE f32 division + floorf: must match numpy reference binning exactly.
        int ix = (int)floorf((xs[k] - ox) / VOXEL_SIZE);
        int iy = (int)floorf((ys[k] - oy) / VOXEL_SIZE);
        int iz = (int)floorf((zs[k] - oz) / VOXEL_SIZE);
        int v = -1; unsigned r = 0;
        if ((unsigned)ix < GRID_W && (unsigned)iy < GRID_L && (unsigned)iz < GRID_H) {
            v = b * NVOX + ix * (GRID_L * GRID_H) + iy * GRID_H + iz;
            r = atomicAdd(&cnt[v], 1u);
        }
        vs[k] = v; rs[k] = r;
    }
    *(int4*)(vidx + pid)  = int4{vs[0], vs[1], vs[2], vs[3]};
    *(uint4*)(rank + pid) = uint4{rs[0], rs[1], rs[2], rs[3]};
}

// Scan level 1: per-2048-chunk exclusive partials + chunk totals.
// Also emits the occupancy output plane (it reads every count anyway).
__global__ void k_scan1(const unsigned* __restrict__ cnt,
                        unsigned* __restrict__ offsets,
                        unsigned* __restrict__ sums,
                        float*    __restrict__ occ)      // [TOTVOX] in d_out
{
    __shared__ unsigned s[SCAN_TPB];
    int t = threadIdx.x;
    int base = blockIdx.x * SCAN_CHUNK + t * SCAN_EPT;

    uint4 a = ((const uint4*)(cnt + base))[0];
    uint4 c = ((const uint4*)(cnt + base))[1];
    unsigned e[SCAN_EPT] = {a.x, a.y, a.z, a.w, c.x, c.y, c.z, c.w};

    float4 oc0, oc1;
    oc0.x = (e[0] >= MIN_PTS) ? 1.f : 0.f;  oc0.y = (e[1] >= MIN_PTS) ? 1.f : 0.f;
    oc0.z = (e[2] >= MIN_PTS) ? 1.f : 0.f;  oc0.w = (e[3] >= MIN_PTS) ? 1.f : 0.f;
    oc1.x = (e[4] >= MIN_PTS) ? 1.f : 0.f;  oc1.y = (e[5] >= MIN_PTS) ? 1.f : 0.f;
    oc1.z = (e[6] >= MIN_PTS) ? 1.f : 0.f;  oc1.w = (e[7] >= MIN_PTS) ? 1.f : 0.f;
    ((float4*)(occ + base))[0] = oc0;
    ((float4*)(occ + base))[1] = oc1;

    unsigned tot = 0;
    #pragma unroll
    for (int k = 0; k < SCAN_EPT; ++k) { unsigned v = e[k]; e[k] = tot; tot += v; }

    s[t] = tot;
    __syncthreads();
    #pragma unroll
    for (int off = 1; off < SCAN_TPB; off <<= 1) {
        unsigned v = (t >= off) ? s[t - off] : 0u;
        __syncthreads();
        s[t] += v;
        __syncthreads();
    }
    unsigned prefix = s[t] - tot;   // exclusive within chunk
    #pragma unroll
    for (int k = 0; k < SCAN_EPT; ++k) e[k] += prefix;

    ((uint4*)(offsets + base))[0] = uint4{e[0], e[1], e[2], e[3]};
    ((uint4*)(offsets + base))[1] = uint4{e[4], e[5], e[6], e[7]};

    if (t == SCAN_TPB - 1) sums[blockIdx.x] = s[t];
}

// Scan level 2: exclusive scan of the 864 chunk sums (single block).
// Consumers add sums[v >> 11] themselves. sums[SCAN_BLKS] = grand total
// (sentinel so k = start(v+1)-start(v) works for the last voxel).
__global__ void k_scan2(unsigned* __restrict__ sums) {
    __shared__ unsigned s[1024];
    int t = threadIdx.x;
    unsigned my = (t < SCAN_BLKS) ? sums[t] : 0u;
    s[t] = my;
    __syncthreads();
    #pragma unroll
    for (int off = 1; off < 1024; off <<= 1) {
        unsigned v = (t >= off) ? s[t - off] : 0u;
        __syncthreads();
        s[t] += v;
        __syncthreads();
    }
    if (t < SCAN_BLKS) sums[t] = s[t] - my;   // exclusive
    if (t == SCAN_BLKS - 1) sums[SCAN_BLKS] = s[t];  // inclusive grand total
}

// Scatter each in-bounds point's index-within-batch into its voxel segment.
// No atomics: pos = chunk-local offset + chunk prefix + rank-from-histogram.
__global__ void k_scatter_ids(const int*      __restrict__ vidx,    // [TOTPTS]
                              const unsigned* __restrict__ rank,    // [TOTPTS]
                              const unsigned* __restrict__ offsets, // [TOTVOX]
                              const unsigned* __restrict__ sums,    // [SCAN_BLKS]
                              int*            __restrict__ ids)     // [TOTPTS]
{
    int id = blockIdx.x * blockDim.x + threadIdx.x;
    if (id >= TOTPTS) return;
    int v = vidx[id];
    if (v < 0) return;
    unsigned pos = offsets[v] + sums[v >> 11] + rank[id];
    int b = id / NPTS;
    ids[pos] = id - b * NPTS;   // n within batch (b recoverable from segment)
}

// Gather + finalize: one thread per (batch, channel-quad, voxel).
// XCD-pinned plane groups: blocks dispatch round-robin over 8 XCDs
// (bid & 7); each XCD owns 2 of the 16 (b, cquad) groups and walks them
// sequentially, so its L2 holds just 4 attr planes (~4.8 MB) while every
// line is consumed. Writes are fully coalesced plane-major.
__global__ void k_gather4(const float*    __restrict__ attrs,   // [B,C,NPTS]
                          const int*      __restrict__ ids,     // [TOTPTS]
                          const unsigned* __restrict__ offsets, // [TOTVOX+1]
                          const unsigned* __restrict__ sums,    // [SCAN_BLKS+1]
                          float*          __restrict__ data)    // [B,C,NVOX]
{
    int bid = blockIdx.x;              // [0, GATHER_BLKS)
    int xcd = bid & 7;
    int seq = bid >> 3;                // [0, 3456)
    int gi  = seq / GBLK_PER_PLANE;    // 0..1
    int within = seq - gi * GBLK_PER_PLANE;
    int grp = xcd * 2 + gi;            // [0, 16)
    int b   = grp >> 2;
    int cq  = grp & 3;                 // channels cq*4 .. cq*4+3
    int v   = within * 256 + threadIdx.x;
    int vox = b * NVOX + v;

    unsigned s0 = offsets[vox] + sums[vox >> 11];
    unsigned s1 = offsets[vox + 1] + sums[(vox + 1) >> 11];
    unsigned k = s1 - s0;              // == cnt[vox]

    float m0 = 0.f, m1 = 0.f, m2 = 0.f, m3 = 0.f;
    if (k >= MIN_PTS) {
        const float ninf = -__builtin_inff();
        m0 = m1 = m2 = m3 = ninf;
        const float* p0 = attrs + (size_t)(b * CHANS + cq * 4) * NPTS;
        const float* p1 = p0 + NPTS;
        const float* p2 = p1 + NPTS;
        const float* p3 = p2 + NPTS;
        for (unsigned j = 0; j < k; ++j) {
            int n = ids[s0 + j];
            m0 = fmaxf(m0, p0[n]);
            m1 = fmaxf(m1, p1[n]);
            m2 = fmaxf(m2, p2[n]);
            m3 = fmaxf(m3, p3[n]);
        }
        if (!isfinite(m0)) m0 = 0.f;
        if (!isfinite(m1)) m1 = 0.f;
        if (!isfinite(m2)) m2 = 0.f;
        if (!isfinite(m3)) m3 = 0.f;
    }

    float* db = data + (size_t)(b * CHANS + cq * 4) * NVOX + v;
    db[0 * (size_t)NVOX] = m0;
    db[1 * (size_t)NVOX] = m1;
    db[2 * (size_t)NVOX] = m2;
    db[3 * (size_t)NVOX] = m3;
}

// ============================== fallback path (round-1) ==============================

__device__ __forceinline__ unsigned flip_f32(float f) {
    unsigned u = __float_as_uint(f);
    unsigned mask = (unsigned)(-(int)(u >> 31)) | 0x80000000u;
    return u ^ mask;
}
__device__ __forceinline__ float unflip_f32(unsigned u) {
    unsigned mask = ((u >> 31) - 1u) | 0x80000000u;
    return __uint_as_float(u ^ mask);
}
#define FLIP_NEG_INF 0x007FFFFFu

__global__ void pv_init(uint4* __restrict__ out) {
    const int DATA4 = BATCH * CHANS * NVOX / 4;
    const int TOT4  = BATCH * (CHANS + 1) * NVOX / 4;
    int i = blockIdx.x * blockDim.x + threadIdx.x;
    if (i < TOT4) {
        unsigned val = (i < DATA4) ? FLIP_NEG_INF : 0u;
        out[i] = uint4{val, val, val, val};
    }
}

__global__ void pv_scatter(const float* __restrict__ coords,
                           const float* __restrict__ attrs,
                           const float* __restrict__ origin,
                           unsigned*    __restrict__ data_u,
                           unsigned*    __restrict__ cnt)
{
    int id = blockIdx.x * blockDim.x + threadIdx.x;
    if (id >= TOTPTS) return;
    int b = id / NPTS;
    int n = id - b * NPTS;
    const float* cb = coords + (size_t)b * 3 * NPTS;
    float x = cb[n], y = cb[NPTS + n], z = cb[2 * NPTS + n];
    float ox = origin[b * 3 + 0], oy = origin[b * 3 + 1], oz = origin[b * 3 + 2];
    int ix = (int)floorf((x - ox) / VOXEL_SIZE);
    int iy = (int)floorf((y - oy) / VOXEL_SIZE);
    int iz = (int)floorf((z - oz) / VOXEL_SIZE);
    if ((unsigned)ix < GRID_W && (unsigned)iy < GRID_L && (unsigned)iz < GRID_H) {
        int flat = ix * (GRID_L * GRID_H) + iy * GRID_H + iz;
        atomicAdd(&cnt[b * NVOX + flat], 1u);
        const float* ab = attrs + (size_t)b * CHANS * NPTS + n;
        unsigned*    db = data_u + (size_t)b * CHANS * NVOX + flat;
        #pragma unroll
        for (int c = 0; c < CHANS; ++c)
            atomicMax(&db[(size_t)c * NVOX], flip_f32(ab[(size_t)c * NPTS]));
    }
}

__global__ void pv_finalize(unsigned* __restrict__ data_u,
                            unsigned* __restrict__ cnt_u)
{
    int id = blockIdx.x * blockDim.x + threadIdx.x;
    if (id >= TOTVOX) return;
    int b = id / NVOX;
    int v = id - b * NVOX;
    unsigned cnt = cnt_u[id];
    bool occ = (cnt >= MIN_PTS);
    ((float*)cnt_u)[id] = occ ? 1.0f : 0.0f;
    unsigned* db = data_u + (size_t)b * CHANS * NVOX + v;
    #pragma unroll
    for (int c = 0; c < CHANS; ++c) {
        float f = unflip_f32(db[(size_t)c * NVOX]);
        ((float*)db)[(size_t)c * NVOX] = (occ && isfinite(f)) ? f : 0.0f;
    }
}

// ============================== launch ==============================

extern "C" void kernel_launch(void* const* d_in, const int* in_sizes, int n_in,
                              void* d_out, int out_size, void* d_ws, size_t ws_size,
                              hipStream_t stream) {
    const float* coords = (const float*)d_in[0];  // [4,3,480,640]
    const float* attrs  = (const float*)d_in[1];  // [4,16,480,640]
    const float* origin = (const float*)d_in[2];  // [4,3]

    float* out = (float*)d_out;
    float* data = out;                                          // [B,C,NVOX]
    float* occ  = out + (size_t)BATCH * CHANS * NVOX;           // [B,NVOX]

    if (ws_size >= WS_NEEDED) {
        char* ws = (char*)d_ws;
        unsigned* cnt     = (unsigned*)(ws + WS_CNT);
        unsigned* offsets = (unsigned*)(ws + WS_OFFSETS);
        int*      vidx    = (int*)(ws + WS_VIDX);
        unsigned* rank    = (unsigned*)(ws + WS_RANK);
        int*      ids     = (int*)(ws + WS_IDS);
        unsigned* sums    = (unsigned*)(ws + WS_SUMS);

        k_zero_cnt<<<(TOTVOX / 4 + 255) / 256, 256, 0, stream>>>((uint4*)cnt, offsets);
        k_vidx_hist4<<<(TOTPTS / 4 + 255) / 256, 256, 0, stream>>>(coords, origin, vidx, rank, cnt);
        k_scan1<<<SCAN_BLKS, SCAN_TPB, 0, stream>>>(cnt, offsets, sums, occ);
        k_scan2<<<1, 1024, 0, stream>>>(sums);
        k_scatter_ids<<<(TOTPTS + 255) / 256, 256, 0, stream>>>(vidx, rank, offsets, sums, ids);
        k_gather4<<<GATHER_BLKS, 256, 0, stream>>>(attrs, ids, offsets, sums, data);
    } else {
        unsigned* data_u = (unsigned*)data;
        unsigned* cnt    = (unsigned*)occ;
        const int TOT4 = BATCH * (CHANS + 1) * NVOX / 4;
        pv_init<<<(TOT4 + 255) / 256, 256, 0, stream>>>((uint4*)d_out);
        pv_scatter<<<(TOTPTS + 255) / 256, 256, 0, stream>>>(coords, attrs, origin, data_u, cnt);
        pv_finalize<<<(TOTVOX + 255) / 256, 256, 0, stream>>>(data_u, cnt);
    }
}

// Round 5
// 343.225 us; speedup vs baseline: 1.1411x; 1.1348x over previous
//
#include <hip/hip_runtime.h>
#include <cstdint>
#include <math.h>

// Problem constants (from reference)
#define GRID_W 96
#define GRID_L 96
#define GRID_H 48
#define NVOX (GRID_W * GRID_L * GRID_H)   // 442368
#define VOXEL_SIZE 0.05f
#define MIN_PTS 10
#define BATCH 4
#define CHANS 16
#define NPTS (480 * 640)                  // 307200 points per batch
#define TOTPTS (BATCH * NPTS)             // 1228800
#define TOTVOX (BATCH * NVOX)             // 1769472

// Scan geometry: 864 blocks x 256 threads x 8 elems = 1769472 exactly.
#define SCAN_BLKS 864
#define SCAN_TPB 256
#define SCAN_EPT 8
#define SCAN_CHUNK (SCAN_TPB * SCAN_EPT)  // 2048

// ---- workspace layout (bytes) ----
// offsets doubles as the count buffer (scan runs in-place).
#define WS_OFFSETS 0
#define WS_VR      ((TOTVOX + 4) * 4)                 //  7,077,904 (16B aligned)
#define WS_ROWS    (WS_VR + TOTPTS * 4)               // 11,993,104 (16B aligned)
#define WS_SUMS    (WS_ROWS + (size_t)TOTPTS * CHANS * 4)  // 90,636,304
#define WS_NEEDED  ((size_t)(WS_SUMS + 4096))         // ~90.64 MB (== round-1 budget, proven available)

// ============================== fast path ==============================

__global__ void k_zero(uint4* __restrict__ off4, unsigned* __restrict__ offsets) {
    int i = blockIdx.x * blockDim.x + threadIdx.x;
    if (i < TOTVOX / 4) off4[i] = uint4{0u, 0u, 0u, 0u};
    if (i == 0) {  // sentinel words past the end
        offsets[TOTVOX + 0] = 0u; offsets[TOTVOX + 1] = 0u;
        offsets[TOTVOX + 2] = 0u; offsets[TOTVOX + 3] = 0u;
    }
}

// Per-point voxel id + histogram, 4 points/thread with float4 coord loads.
// The atomic's return value is the point's rank within its voxel; packed as
// (voxel << 10) | rank  (rank < 1024 — mean occupancy is ~11, huge margin).
// OOB marker: 0xFFFFFFFF (valid packs max out at ~0x6BFFFFFF).
__global__ void k_hist4(const float* __restrict__ coords,   // [B,3,NPTS]
                        const float* __restrict__ origin,   // [B,3]
                        unsigned*    __restrict__ vr,       // [TOTPTS] packed
                        unsigned*    __restrict__ cnt)      // [TOTVOX] (= offsets buf)
{
    int t = blockIdx.x * blockDim.x + threadIdx.x;
    if (t >= TOTPTS / 4) return;
    int pid = t * 4;
    int b = pid / NPTS;          // NPTS % 4 == 0 -> all 4 points same batch
    int n = pid - b * NPTS;

    const float* cb = coords + (size_t)b * 3 * NPTS;
    float4 X = *(const float4*)(cb + n);
    float4 Y = *(const float4*)(cb + NPTS + n);
    float4 Z = *(const float4*)(cb + 2 * NPTS + n);
    float ox = origin[b * 3 + 0];
    float oy = origin[b * 3 + 1];
    float oz = origin[b * 3 + 2];

    float xs[4] = {X.x, X.y, X.z, X.w};
    float ys[4] = {Y.x, Y.y, Y.z, Y.w};
    float zs[4] = {Z.x, Z.y, Z.z, Z.w};
    unsigned ps[4];
    #pragma unroll
    for (int k = 0; k < 4; ++k) {
        // IEEE f32 division + floorf: must match numpy reference binning exactly.
        int ix = (int)floorf((xs[k] - ox) / VOXEL_SIZE);
        int iy = (int)floorf((ys[k] - oy) / VOXEL_SIZE);
        int iz = (int)floorf((zs[k] - oz) / VOXEL_SIZE);
        unsigned p = 0xFFFFFFFFu;
        if ((unsigned)ix < GRID_W && (unsigned)iy < GRID_L && (unsigned)iz < GRID_H) {
            int v = b * NVOX + ix * (GRID_L * GRID_H) + iy * GRID_H + iz;
            unsigned r = atomicAdd(&cnt[v], 1u);
            p = ((unsigned)v << 10) | (r & 1023u);
        }
        ps[k] = p;
    }
    *(uint4*)(vr + pid) = uint4{ps[0], ps[1], ps[2], ps[3]};
}

// Scan level 1, IN-PLACE on the count buffer: per-2048-chunk exclusive
// partials + chunk totals. Also emits the occupancy output plane.
__global__ void k_scan1(unsigned* __restrict__ offsets,   // counts in, partial offsets out
                        unsigned* __restrict__ sums,
                        float*    __restrict__ occ)       // [TOTVOX] in d_out
{
    __shared__ unsigned s[SCAN_TPB];
    int t = threadIdx.x;
    int base = blockIdx.x * SCAN_CHUNK + t * SCAN_EPT;

    uint4 a = ((const uint4*)(offsets + base))[0];
    uint4 c = ((const uint4*)(offsets + base))[1];
    unsigned e[SCAN_EPT] = {a.x, a.y, a.z, a.w, c.x, c.y, c.z, c.w};

    float4 oc0, oc1;
    oc0.x = (e[0] >= MIN_PTS) ? 1.f : 0.f;  oc0.y = (e[1] >= MIN_PTS) ? 1.f : 0.f;
    oc0.z = (e[2] >= MIN_PTS) ? 1.f : 0.f;  oc0.w = (e[3] >= MIN_PTS) ? 1.f : 0.f;
    oc1.x = (e[4] >= MIN_PTS) ? 1.f : 0.f;  oc1.y = (e[5] >= MIN_PTS) ? 1.f : 0.f;
    oc1.z = (e[6] >= MIN_PTS) ? 1.f : 0.f;  oc1.w = (e[7] >= MIN_PTS) ? 1.f : 0.f;
    ((float4*)(occ + base))[0] = oc0;
    ((float4*)(occ + base))[1] = oc1;

    unsigned tot = 0;
    #pragma unroll
    for (int k = 0; k < SCAN_EPT; ++k) { unsigned v = e[k]; e[k] = tot; tot += v; }

    s[t] = tot;
    __syncthreads();
    #pragma unroll
    for (int off = 1; off < SCAN_TPB; off <<= 1) {
        unsigned v = (t >= off) ? s[t - off] : 0u;
        __syncthreads();
        s[t] += v;
        __syncthreads();
    }
    unsigned prefix = s[t] - tot;   // exclusive within chunk
    #pragma unroll
    for (int k = 0; k < SCAN_EPT; ++k) e[k] += prefix;

    ((uint4*)(offsets + base))[0] = uint4{e[0], e[1], e[2], e[3]};
    ((uint4*)(offsets + base))[1] = uint4{e[4], e[5], e[6], e[7]};

    if (t == SCAN_TPB - 1) sums[blockIdx.x] = s[t];
}

// Scan level 2: exclusive scan of the 864 chunk sums (single block).
// Consumers add sums[v >> 11] themselves. sums[SCAN_BLKS] = grand total.
__global__ void k_scan2(unsigned* __restrict__ sums) {
    __shared__ unsigned s[1024];
    int t = threadIdx.x;
    unsigned my = (t < SCAN_BLKS) ? sums[t] : 0u;
    s[t] = my;
    __syncthreads();
    #pragma unroll
    for (int off = 1; off < 1024; off <<= 1) {
        unsigned v = (t >= off) ? s[t - off] : 0u;
        __syncthreads();
        s[t] += v;
        __syncthreads();
    }
    if (t < SCAN_BLKS) sums[t] = s[t] - my;          // exclusive
    if (t == SCAN_BLKS - 1) sums[SCAN_BLKS] = s[t];  // grand total sentinel
}

// Scatter each in-bounds point's full 16-channel row into its voxel segment.
// No atomics. Each 64 B destination line is written entirely by ONE thread
// (pos*64 is 64B-aligned) -> no RMW, no cross-XCD ping-pong.
__global__ void k_scatter_rows(const float*    __restrict__ attrs,   // [B,C,NPTS]
                               const unsigned* __restrict__ vr,      // [TOTPTS] packed
                               const unsigned* __restrict__ offsets, // [TOTVOX]
                               const unsigned* __restrict__ sums,    // [SCAN_BLKS+1]
                               float*          __restrict__ rows)    // [TOTPTS,16]
{
    int id = blockIdx.x * blockDim.x + threadIdx.x;
    if (id >= TOTPTS) return;
    unsigned p = vr[id];
    if (p == 0xFFFFFFFFu) return;
    unsigned v = p >> 10;
    unsigned r = p & 1023u;
    unsigned pos = offsets[v] + sums[v >> 11] + r;

    int b = id / NPTS;
    int n = id - b * NPTS;
    const float* ab = attrs + (size_t)b * CHANS * NPTS + n;
    float4 r0, r1, r2, r3;
    r0.x = ab[0 * (size_t)NPTS];  r0.y = ab[1 * (size_t)NPTS];
    r0.z = ab[2 * (size_t)NPTS];  r0.w = ab[3 * (size_t)NPTS];
    r1.x = ab[4 * (size_t)NPTS];  r1.y = ab[5 * (size_t)NPTS];
    r1.z = ab[6 * (size_t)NPTS];  r1.w = ab[7 * (size_t)NPTS];
    r2.x = ab[8 * (size_t)NPTS];  r2.y = ab[9 * (size_t)NPTS];
    r2.z = ab[10 * (size_t)NPTS]; r2.w = ab[11 * (size_t)NPTS];
    r3.x = ab[12 * (size_t)NPTS]; r3.y = ab[13 * (size_t)NPTS];
    r3.z = ab[14 * (size_t)NPTS]; r3.w = ab[15 * (size_t)NPTS];

    float4* dst = (float4*)(rows + (size_t)pos * CHANS);
    dst[0] = r0; dst[1] = r1; dst[2] = r2; dst[3] = r3;
}

// Gather + finalize: ONE thread per voxel owns all 16 channels.
// Segment reads are sequential (adjacent voxels = adjacent segments; a wave
// streams ~45 KB contiguous rows). Every rows-line is read exactly once ->
// pure streaming, no cache-reuse requirement. 16 coalesced per-channel stores.
__global__ void k_gather_rows(const float*    __restrict__ rows,    // [TOTPTS,16]
                              const unsigned* __restrict__ offsets, // [TOTVOX+1]
                              const unsigned* __restrict__ sums,    // [SCAN_BLKS+1]
                              float*          __restrict__ data)    // [B,C,NVOX]
{
    int vox = blockIdx.x * blockDim.x + threadIdx.x;
    if (vox >= TOTVOX) return;

    unsigned s0 = offsets[vox] + sums[vox >> 11];
    unsigned s1 = offsets[vox + 1] + sums[(vox + 1) >> 11];
    unsigned k = s1 - s0;   // == count[vox]

    float4 m0 = {0.f,0.f,0.f,0.f}, m1 = m0, m2 = m0, m3 = m0;
    if (k >= MIN_PTS) {
        const float ninf = -__builtin_inff();
        m0 = m1 = m2 = m3 = float4{ninf, ninf, ninf, ninf};
        const float4* seg = (const float4*)(rows + (size_t)s0 * CHANS);
        for (unsigned j = 0; j < k; ++j) {
            float4 r0 = seg[0], r1 = seg[1], r2 = seg[2], r3 = seg[3];
            seg += 4;
            m0.x = fmaxf(m0.x, r0.x); m0.y = fmaxf(m0.y, r0.y);
            m0.z = fmaxf(m0.z, r0.z); m0.w = fmaxf(m0.w, r0.w);
            m1.x = fmaxf(m1.x, r1.x); m1.y = fmaxf(m1.y, r1.y);
            m1.z = fmaxf(m1.z, r1.z); m1.w = fmaxf(m1.w, r1.w);
            m2.x = fmaxf(m2.x, r2.x); m2.y = fmaxf(m2.y, r2.y);
            m2.z = fmaxf(m2.z, r2.z); m2.w = fmaxf(m2.w, r2.w);
            m3.x = fmaxf(m3.x, r3.x); m3.y = fmaxf(m3.y, r3.y);
            m3.z = fmaxf(m3.z, r3.z); m3.w = fmaxf(m3.w, r3.w);
        }
        float mv[16] = {m0.x,m0.y,m0.z,m0.w, m1.x,m1.y,m1.z,m1.w,
                        m2.x,m2.y,m2.z,m2.w, m3.x,m3.y,m3.z,m3.w};
        #pragma unroll
        for (int c = 0; c < CHANS; ++c) if (!isfinite(mv[c])) mv[c] = 0.f;
        m0 = float4{mv[0],mv[1],mv[2],mv[3]};   m1 = float4{mv[4],mv[5],mv[6],mv[7]};
        m2 = float4{mv[8],mv[9],mv[10],mv[11]}; m3 = float4{mv[12],mv[13],mv[14],mv[15]};
    }

    int b = vox / NVOX;                 // NVOX % 64 == 0 -> wave-uniform b
    int v = vox - b * NVOX;
    float* db = data + (size_t)b * CHANS * NVOX + v;
    db[0 * (size_t)NVOX] = m0.x;  db[1 * (size_t)NVOX] = m0.y;
    db[2 * (size_t)NVOX] = m0.z;  db[3 * (size_t)NVOX] = m0.w;
    db[4 * (size_t)NVOX] = m1.x;  db[5 * (size_t)NVOX] = m1.y;
    db[6 * (size_t)NVOX] = m1.z;  db[7 * (size_t)NVOX] = m1.w;
    db[8 * (size_t)NVOX] = m2.x;  db[9 * (size_t)NVOX] = m2.y;
    db[10 * (size_t)NVOX] = m2.z; db[11 * (size_t)NVOX] = m2.w;
    db[12 * (size_t)NVOX] = m3.x; db[13 * (size_t)NVOX] = m3.y;
    db[14 * (size_t)NVOX] = m3.z; db[15 * (size_t)NVOX] = m3.w;
}

// ============================== fallback path (round-1) ==============================

__device__ __forceinline__ unsigned flip_f32(float f) {
    unsigned u = __float_as_uint(f);
    unsigned mask = (unsigned)(-(int)(u >> 31)) | 0x80000000u;
    return u ^ mask;
}
__device__ __forceinline__ float unflip_f32(unsigned u) {
    unsigned mask = ((u >> 31) - 1u) | 0x80000000u;
    return __uint_as_float(u ^ mask);
}
#define FLIP_NEG_INF 0x007FFFFFu

__global__ void pv_init(uint4* __restrict__ out) {
    const int DATA4 = BATCH * CHANS * NVOX / 4;
    const int TOT4  = BATCH * (CHANS + 1) * NVOX / 4;
    int i = blockIdx.x * blockDim.x + threadIdx.x;
    if (i < TOT4) {
        unsigned val = (i < DATA4) ? FLIP_NEG_INF : 0u;
        out[i] = uint4{val, val, val, val};
    }
}

__global__ void pv_scatter(const float* __restrict__ coords,
                           const float* __restrict__ attrs,
                           const float* __restrict__ origin,
                           unsigned*    __restrict__ data_u,
                           unsigned*    __restrict__ cnt)
{
    int id = blockIdx.x * blockDim.x + threadIdx.x;
    if (id >= TOTPTS) return;
    int b = id / NPTS;
    int n = id - b * NPTS;
    const float* cb = coords + (size_t)b * 3 * NPTS;
    float x = cb[n], y = cb[NPTS + n], z = cb[2 * NPTS + n];
    float ox = origin[b * 3 + 0], oy = origin[b * 3 + 1], oz = origin[b * 3 + 2];
    int ix = (int)floorf((x - ox) / VOXEL_SIZE);
    int iy = (int)floorf((y - oy) / VOXEL_SIZE);
    int iz = (int)floorf((z - oz) / VOXEL_SIZE);
    if ((unsigned)ix < GRID_W && (unsigned)iy < GRID_L && (unsigned)iz < GRID_H) {
        int flat = ix * (GRID_L * GRID_H) + iy * GRID_H + iz;
        atomicAdd(&cnt[b * NVOX + flat], 1u);
        const float* ab = attrs + (size_t)b * CHANS * NPTS + n;
        unsigned*    db = data_u + (size_t)b * CHANS * NVOX + flat;
        #pragma unroll
        for (int c = 0; c < CHANS; ++c)
            atomicMax(&db[(size_t)c * NVOX], flip_f32(ab[(size_t)c * NPTS]));
    }
}

__global__ void pv_finalize(unsigned* __restrict__ data_u,
                            unsigned* __restrict__ cnt_u)
{
    int id = blockIdx.x * blockDim.x + threadIdx.x;
    if (id >= TOTVOX) return;
    int b = id / NVOX;
    int v = id - b * NVOX;
    unsigned cnt = cnt_u[id];
    bool occ = (cnt >= MIN_PTS);
    ((float*)cnt_u)[id] = occ ? 1.0f : 0.0f;
    unsigned* db = data_u + (size_t)b * CHANS * NVOX + v;
    #pragma unroll
    for (int c = 0; c < CHANS; ++c) {
        float f = unflip_f32(db[(size_t)c * NVOX]);
        ((float*)db)[(size_t)c * NVOX] = (occ && isfinite(f)) ? f : 0.0f;
    }
}

// ============================== launch ==============================

extern "C" void kernel_launch(void* const* d_in, const int* in_sizes, int n_in,
                              void* d_out, int out_size, void* d_ws, size_t ws_size,
                              hipStream_t stream) {
    const float* coords = (const float*)d_in[0];  // [4,3,480,640]
    const float* attrs  = (const float*)d_in[1];  // [4,16,480,640]
    const float* origin = (const float*)d_in[2];  // [4,3]

    float* out = (float*)d_out;
    float* data = out;                                          // [B,C,NVOX]
    float* occ  = out + (size_t)BATCH * CHANS * NVOX;           // [B,NVOX]

    if (ws_size >= WS_NEEDED) {
        char* ws = (char*)d_ws;
        unsigned* offsets = (unsigned*)(ws + WS_OFFSETS);  // counts -> offsets (in-place)
        unsigned* vr      = (unsigned*)(ws + WS_VR);
        float*    rows    = (float*)(ws + WS_ROWS);
        unsigned* sums    = (unsigned*)(ws + WS_SUMS);

        k_zero<<<(TOTVOX / 4 + 255) / 256, 256, 0, stream>>>((uint4*)offsets, offsets);
        k_hist4<<<(TOTPTS / 4 + 255) / 256, 256, 0, stream>>>(coords, origin, vr, offsets);
        k_scan1<<<SCAN_BLKS, SCAN_TPB, 0, stream>>>(offsets, sums, occ);
        k_scan2<<<1, 1024, 0, stream>>>(sums);
        k_scatter_rows<<<(TOTPTS + 255) / 256, 256, 0, stream>>>(attrs, vr, offsets, sums, rows);
        k_gather_rows<<<(TOTVOX + 255) / 256, 256, 0, stream>>>(rows, offsets, sums, data);
    } else {
        unsigned* data_u = (unsigned*)data;
        unsigned* cnt    = (unsigned*)occ;
        const int TOT4 = BATCH * (CHANS + 1) * NVOX / 4;
        pv_init<<<(TOT4 + 255) / 256, 256, 0, stream>>>((uint4*)d_out);
        pv_scatter<<<(TOTPTS + 255) / 256, 256, 0, stream>>>(coords, attrs, origin, data_u, cnt);
        pv_finalize<<<(TOTVOX + 255) / 256, 256, 0, stream>>>(data_u, cnt);
    }
}

// Round 6
// 337.282 us; speedup vs baseline: 1.1612x; 1.0176x over previous
//
#include <hip/hip_runtime.h>
#include <cstdint>
#include <math.h>

// Problem constants (from reference)
#define GRID_W 96
#define GRID_L 96
#define GRID_H 48
#define NVOX (GRID_W * GRID_L * GRID_H)   // 442368
#define VOXEL_SIZE 0.05f
#define MIN_PTS 10
#define BATCH 4
#define CHANS 16
#define NPTS (480 * 640)                  // 307200 points per batch
#define TOTPTS (BATCH * NPTS)             // 1228800
#define TOTVOX (BATCH * NVOX)             // 1769472

// Scan geometry: 864 blocks x 256 threads x 8 elems = 1769472 exactly.
#define SCAN_BLKS 864
#define SCAN_TPB 256
#define SCAN_EPT 8
#define SCAN_CHUNK (SCAN_TPB * SCAN_EPT)  // 2048

#define ROWW 8   // uint words per bf16 row (16 channels x 2B = 32B)

// ---- workspace layout (bytes) ----
// offsets doubles as the count buffer (scan runs in-place).
#define WS_OFFSETS 0
#define WS_VR      ((TOTVOX + 4) * 4)                      //  7,077,904 (16B aligned)
#define WS_ROWS    (WS_VR + TOTPTS * 4)                    // 11,993,104 (16B aligned)
#define WS_SUMS    (WS_ROWS + (size_t)TOTPTS * ROWW * 4)   // 51,314,704
#define WS_NEEDED  ((size_t)(WS_SUMS + 4096))              // ~51.3 MB (< proven 90.6 MB budget)

// bf16 round-to-nearest-even (inputs finite)
__device__ __forceinline__ unsigned bf16_rtne(float f) {
    unsigned u = __float_as_uint(f);
    return (u + 0x7FFFu + ((u >> 16) & 1u)) >> 16;
}
__device__ __forceinline__ unsigned pack2(float lo, float hi) {
    return bf16_rtne(lo) | (bf16_rtne(hi) << 16);
}

// ============================== fast path ==============================

// Per-point voxel id + histogram, 4 points/thread with float4 coord loads.
// The atomic's return value is the point's rank within its voxel; packed as
// (voxel << 10) | rank  (rank < 1024 — mean occupancy ~11, huge margin).
// OOB marker: 0xFFFFFFFF (valid packs max out at ~0x6BFFFFFF).
__global__ void k_hist4(const float* __restrict__ coords,   // [B,3,NPTS]
                        const float* __restrict__ origin,   // [B,3]
                        unsigned*    __restrict__ vr,       // [TOTPTS] packed
                        unsigned*    __restrict__ cnt)      // [TOTVOX] (= offsets buf)
{
    int t = blockIdx.x * blockDim.x + threadIdx.x;
    if (t >= TOTPTS / 4) return;
    int pid = t * 4;
    int b = pid / NPTS;          // NPTS % 4 == 0 -> all 4 points same batch
    int n = pid - b * NPTS;

    const float* cb = coords + (size_t)b * 3 * NPTS;
    float4 X = *(const float4*)(cb + n);
    float4 Y = *(const float4*)(cb + NPTS + n);
    float4 Z = *(const float4*)(cb + 2 * NPTS + n);
    float ox = origin[b * 3 + 0];
    float oy = origin[b * 3 + 1];
    float oz = origin[b * 3 + 2];

    float xs[4] = {X.x, X.y, X.z, X.w};
    float ys[4] = {Y.x, Y.y, Y.z, Y.w};
    float zs[4] = {Z.x, Z.y, Z.z, Z.w};
    unsigned ps[4];
    #pragma unroll
    for (int k = 0; k < 4; ++k) {
        // IEEE f32 division + floorf: must match numpy reference binning exactly.
        int ix = (int)floorf((xs[k] - ox) / VOXEL_SIZE);
        int iy = (int)floorf((ys[k] - oy) / VOXEL_SIZE);
        int iz = (int)floorf((zs[k] - oz) / VOXEL_SIZE);
        unsigned p = 0xFFFFFFFFu;
        if ((unsigned)ix < GRID_W && (unsigned)iy < GRID_L && (unsigned)iz < GRID_H) {
            int v = b * NVOX + ix * (GRID_L * GRID_H) + iy * GRID_H + iz;
            unsigned r = atomicAdd(&cnt[v], 1u);
            p = ((unsigned)v << 10) | (r & 1023u);
        }
        ps[k] = p;
    }
    *(uint4*)(vr + pid) = uint4{ps[0], ps[1], ps[2], ps[3]};
}

// Scan level 1, IN-PLACE on the count buffer: per-2048-chunk exclusive
// partials + chunk totals. Also emits the occupancy output plane.
__global__ void k_scan1(unsigned* __restrict__ offsets,   // counts in, partial offsets out
                        unsigned* __restrict__ sums,
                        float*    __restrict__ occ)       // [TOTVOX] in d_out
{
    __shared__ unsigned s[SCAN_TPB];
    int t = threadIdx.x;
    int base = blockIdx.x * SCAN_CHUNK + t * SCAN_EPT;

    uint4 a = ((const uint4*)(offsets + base))[0];
    uint4 c = ((const uint4*)(offsets + base))[1];
    unsigned e[SCAN_EPT] = {a.x, a.y, a.z, a.w, c.x, c.y, c.z, c.w};

    float4 oc0, oc1;
    oc0.x = (e[0] >= MIN_PTS) ? 1.f : 0.f;  oc0.y = (e[1] >= MIN_PTS) ? 1.f : 0.f;
    oc0.z = (e[2] >= MIN_PTS) ? 1.f : 0.f;  oc0.w = (e[3] >= MIN_PTS) ? 1.f : 0.f;
    oc1.x = (e[4] >= MIN_PTS) ? 1.f : 0.f;  oc1.y = (e[5] >= MIN_PTS) ? 1.f : 0.f;
    oc1.z = (e[6] >= MIN_PTS) ? 1.f : 0.f;  oc1.w = (e[7] >= MIN_PTS) ? 1.f : 0.f;
    ((float4*)(occ + base))[0] = oc0;
    ((float4*)(occ + base))[1] = oc1;

    unsigned tot = 0;
    #pragma unroll
    for (int k = 0; k < SCAN_EPT; ++k) { unsigned v = e[k]; e[k] = tot; tot += v; }

    s[t] = tot;
    __syncthreads();
    #pragma unroll
    for (int off = 1; off < SCAN_TPB; off <<= 1) {
        unsigned v = (t >= off) ? s[t - off] : 0u;
        __syncthreads();
        s[t] += v;
        __syncthreads();
    }
    unsigned prefix = s[t] - tot;   // exclusive within chunk
    #pragma unroll
    for (int k = 0; k < SCAN_EPT; ++k) e[k] += prefix;

    ((uint4*)(offsets + base))[0] = uint4{e[0], e[1], e[2], e[3]};
    ((uint4*)(offsets + base))[1] = uint4{e[4], e[5], e[6], e[7]};

    if (t == SCAN_TPB - 1) sums[blockIdx.x] = s[t];
}

// Scan level 2: exclusive scan of the 864 chunk sums (single block).
// Consumers add sums[v >> 11] themselves. sums[SCAN_BLKS] = grand total.
__global__ void k_scan2(unsigned* __restrict__ sums) {
    __shared__ unsigned s[1024];
    int t = threadIdx.x;
    unsigned my = (t < SCAN_BLKS) ? sums[t] : 0u;
    s[t] = my;
    __syncthreads();
    #pragma unroll
    for (int off = 1; off < 1024; off <<= 1) {
        unsigned v = (t >= off) ? s[t - off] : 0u;
        __syncthreads();
        s[t] += v;
        __syncthreads();
    }
    if (t < SCAN_BLKS) sums[t] = s[t] - my;          // exclusive
    if (t == SCAN_BLKS - 1) sums[SCAN_BLKS] = s[t];  // grand total sentinel
}

// Scatter 4 points/thread: pack each in-bounds point's 16 channels to bf16
// (32 B row) and store into its voxel segment. No atomics; two 16 B stores
// per row. float4 attr loads (4 points x 2 channels per load pair).
__global__ void k_scatter_rows4(const float*    __restrict__ attrs,   // [B,C,NPTS]
                                const unsigned* __restrict__ vr,      // [TOTPTS] packed
                                const unsigned* __restrict__ offsets, // [TOTVOX]
                                const unsigned* __restrict__ sums,    // [SCAN_BLKS+1]
                                unsigned*       __restrict__ rows)    // [TOTPTS,8] words
{
    int t = blockIdx.x * blockDim.x + threadIdx.x;
    if (t >= TOTPTS / 4) return;
    int pid = t * 4;
    int b = pid / NPTS;
    int n = pid - b * NPTS;

    uint4 P = *(const uint4*)(vr + pid);
    unsigned ps[4] = {P.x, P.y, P.z, P.w};
    unsigned pos[4];
    #pragma unroll
    for (int k = 0; k < 4; ++k) {
        pos[k] = 0xFFFFFFFFu;
        if (ps[k] != 0xFFFFFFFFu) {
            unsigned v = ps[k] >> 10;
            pos[k] = offsets[v] + sums[v >> 11] + (ps[k] & 1023u);
        }
    }

    const float* ab = attrs + (size_t)b * CHANS * NPTS + n;
    unsigned w[4][ROWW];
    #pragma unroll
    for (int c = 0; c < CHANS; c += 2) {
        float4 a0 = *(const float4*)(ab + (size_t)c * NPTS);
        float4 a1 = *(const float4*)(ab + (size_t)(c + 1) * NPTS);
        w[0][c >> 1] = pack2(a0.x, a1.x);
        w[1][c >> 1] = pack2(a0.y, a1.y);
        w[2][c >> 1] = pack2(a0.z, a1.z);
        w[3][c >> 1] = pack2(a0.w, a1.w);
    }
    #pragma unroll
    for (int k = 0; k < 4; ++k) {
        if (pos[k] == 0xFFFFFFFFu) continue;
        uint4* dst = (uint4*)(rows + (size_t)pos[k] * ROWW);
        dst[0] = uint4{w[k][0], w[k][1], w[k][2], w[k][3]};
        dst[1] = uint4{w[k][4], w[k][5], w[k][6], w[k][7]};
    }
}

// Gather + finalize: ONE thread per 4 adjacent voxels, owning all 16
// channels. The 4 segments are one contiguous byte range (adjacent voxels =
// adjacent segments) -> pure sequential streaming, every line read once.
// Output: 16 float4 stores (1 KB per wave-instruction), fully coalesced.
__global__ void k_gather_rows4(const unsigned* __restrict__ rows,    // [TOTPTS,8] words
                               const unsigned* __restrict__ offsets, // [TOTVOX+4]
                               const unsigned* __restrict__ sums,    // [SCAN_BLKS+1]
                               float*          __restrict__ data)    // [B,C,NVOX]
{
    int g = blockIdx.x * blockDim.x + threadIdx.x;
    if (g >= TOTVOX / 4) return;
    int vox0 = g * 4;

    // vox0 % 4 == 0 and chunk size 2048 % 4 == 0 -> vox0..vox0+3 same chunk.
    uint4 O = *(const uint4*)(offsets + vox0);
    unsigned base = sums[vox0 >> 11];
    unsigned s[5];
    s[0] = O.x + base; s[1] = O.y + base; s[2] = O.z + base; s[3] = O.w + base;
    s[4] = offsets[vox0 + 4] + sums[(vox0 + 4) >> 11];  // sentinels cover vox0+4==TOTVOX

    float m[4][CHANS];
    #pragma unroll
    for (int q = 0; q < 4; ++q) {
        unsigned k = s[q + 1] - s[q];
        if (k >= MIN_PTS) {
            const float ninf = -__builtin_inff();
            #pragma unroll
            for (int c = 0; c < CHANS; ++c) m[q][c] = ninf;
            const uint4* seg = (const uint4*)(rows + (size_t)s[q] * ROWW);
            for (unsigned j = 0; j < k; ++j) {
                uint4 lo = seg[0], hi = seg[1];
                seg += 2;
                unsigned ww[8] = {lo.x, lo.y, lo.z, lo.w, hi.x, hi.y, hi.z, hi.w};
                #pragma unroll
                for (int h = 0; h < 8; ++h) {
                    float f0 = __uint_as_float(ww[h] << 16);          // even channel
                    float f1 = __uint_as_float(ww[h] & 0xFFFF0000u);  // odd channel
                    m[q][2 * h]     = fmaxf(m[q][2 * h], f0);
                    m[q][2 * h + 1] = fmaxf(m[q][2 * h + 1], f1);
                }
            }
            #pragma unroll
            for (int c = 0; c < CHANS; ++c) if (!isfinite(m[q][c])) m[q][c] = 0.f;
        } else {
            #pragma unroll
            for (int c = 0; c < CHANS; ++c) m[q][c] = 0.f;
        }
    }

    int b = vox0 / NVOX;                 // NVOX % 4 == 0
    int v0 = vox0 - b * NVOX;
    float* db = data + (size_t)b * CHANS * NVOX + v0;
    #pragma unroll
    for (int c = 0; c < CHANS; ++c) {
        *(float4*)(db + (size_t)c * NVOX) = float4{m[0][c], m[1][c], m[2][c], m[3][c]};
    }
}

// ============================== fallback path (round-1) ==============================

__device__ __forceinline__ unsigned flip_f32(float f) {
    unsigned u = __float_as_uint(f);
    unsigned mask = (unsigned)(-(int)(u >> 31)) | 0x80000000u;
    return u ^ mask;
}
__device__ __forceinline__ float unflip_f32(unsigned u) {
    unsigned mask = ((u >> 31) - 1u) | 0x80000000u;
    return __uint_as_float(u ^ mask);
}
#define FLIP_NEG_INF 0x007FFFFFu

__global__ void pv_init(uint4* __restrict__ out) {
    const int DATA4 = BATCH * CHANS * NVOX / 4;
    const int TOT4  = BATCH * (CHANS + 1) * NVOX / 4;
    int i = blockIdx.x * blockDim.x + threadIdx.x;
    if (i < TOT4) {
        unsigned val = (i < DATA4) ? FLIP_NEG_INF : 0u;
        out[i] = uint4{val, val, val, val};
    }
}

__global__ void pv_scatter(const float* __restrict__ coords,
                           const float* __restrict__ attrs,
                           const float* __restrict__ origin,
                           unsigned*    __restrict__ data_u,
                           unsigned*    __restrict__ cnt)
{
    int id = blockIdx.x * blockDim.x + threadIdx.x;
    if (id >= TOTPTS) return;
    int b = id / NPTS;
    int n = id - b * NPTS;
    const float* cb = coords + (size_t)b * 3 * NPTS;
    float x = cb[n], y = cb[NPTS + n], z = cb[2 * NPTS + n];
    float ox = origin[b * 3 + 0], oy = origin[b * 3 + 1], oz = origin[b * 3 + 2];
    int ix = (int)floorf((x - ox) / VOXEL_SIZE);
    int iy = (int)floorf((y - oy) / VOXEL_SIZE);
    int iz = (int)floorf((z - oz) / VOXEL_SIZE);
    if ((unsigned)ix < GRID_W && (unsigned)iy < GRID_L && (unsigned)iz < GRID_H) {
        int flat = ix * (GRID_L * GRID_H) + iy * GRID_H + iz;
        atomicAdd(&cnt[b * NVOX + flat], 1u);
        const float* ab = attrs + (size_t)b * CHANS * NPTS + n;
        unsigned*    db = data_u + (size_t)b * CHANS * NVOX + flat;
        #pragma unroll
        for (int c = 0; c < CHANS; ++c)
            atomicMax(&db[(size_t)c * NVOX], flip_f32(ab[(size_t)c * NPTS]));
    }
}

__global__ void pv_finalize(unsigned* __restrict__ data_u,
                            unsigned* __restrict__ cnt_u)
{
    int id = blockIdx.x * blockDim.x + threadIdx.x;
    if (id >= TOTVOX) return;
    int b = id / NVOX;
    int v = id - b * NVOX;
    unsigned cnt = cnt_u[id];
    bool occ = (cnt >= MIN_PTS);
    ((float*)cnt_u)[id] = occ ? 1.0f : 0.0f;
    unsigned* db = data_u + (size_t)b * CHANS * NVOX + v;
    #pragma unroll
    for (int c = 0; c < CHANS; ++c) {
        float f = unflip_f32(db[(size_t)c * NVOX]);
        ((float*)db)[(size_t)c * NVOX] = (occ && isfinite(f)) ? f : 0.0f;
    }
}

// ============================== launch ==============================

extern "C" void kernel_launch(void* const* d_in, const int* in_sizes, int n_in,
                              void* d_out, int out_size, void* d_ws, size_t ws_size,
                              hipStream_t stream) {
    const float* coords = (const float*)d_in[0];  // [4,3,480,640]
    const float* attrs  = (const float*)d_in[1];  // [4,16,480,640]
    const float* origin = (const float*)d_in[2];  // [4,3]

    float* out = (float*)d_out;
    float* data = out;                                          // [B,C,NVOX]
    float* occ  = out + (size_t)BATCH * CHANS * NVOX;           // [B,NVOX]

    if (ws_size >= WS_NEEDED) {
        char* ws = (char*)d_ws;
        unsigned* offsets = (unsigned*)(ws + WS_OFFSETS);  // counts -> offsets (in-place)
        unsigned* vr      = (unsigned*)(ws + WS_VR);
        unsigned* rows    = (unsigned*)(ws + WS_ROWS);
        unsigned* sums    = (unsigned*)(ws + WS_SUMS);

        // zero counts + the 4 sentinel words past the end
        hipMemsetAsync(offsets, 0, (size_t)(TOTVOX + 4) * 4, stream);
        k_hist4<<<(TOTPTS / 4 + 255) / 256, 256, 0, stream>>>(coords, origin, vr, offsets);
        k_scan1<<<SCAN_BLKS, SCAN_TPB, 0, stream>>>(offsets, sums, occ);
        k_scan2<<<1, 1024, 0, stream>>>(sums);
        k_scatter_rows4<<<(TOTPTS / 4 + 255) / 256, 256, 0, stream>>>(attrs, vr, offsets, sums, rows);
        k_gather_rows4<<<(TOTVOX / 4 + 255) / 256, 256, 0, stream>>>(rows, offsets, sums, data);
    } else {
        unsigned* data_u = (unsigned*)data;
        unsigned* cnt    = (unsigned*)occ;
        const int TOT4 = BATCH * (CHANS + 1) * NVOX / 4;
        pv_init<<<(TOT4 + 255) / 256, 256, 0, stream>>>((uint4*)d_out);
        pv_scatter<<<(TOTPTS + 255) / 256, 256, 0, stream>>>(coords, attrs, origin, data_u, cnt);
        pv_finalize<<<(TOTVOX + 255) / 256, 256, 0, stream>>>(data_u, cnt);
    }
}

// Round 7
// 313.379 us; speedup vs baseline: 1.2498x; 1.0763x over previous
//
#include <hip/hip_runtime.h>
#include <cstdint>
#include <math.h>

// Problem constants (from reference)
#define GRID_W 96
#define GRID_L 96
#define GRID_H 48
#define NVOX (GRID_W * GRID_L * GRID_H)   // 442368
#define VOXEL_SIZE 0.05f
#define MIN_PTS 10
#define BATCH 4
#define CHANS 16
#define NPTS (480 * 640)                  // 307200 points per batch
#define TOTPTS (BATCH * NPTS)             // 1228800
#define TOTVOX (BATCH * NVOX)             // 1769472

// Scan geometry: 864 blocks x 256 threads x 8 elems = 1769472 exactly.
#define SCAN_BLKS 864
#define SCAN_TPB 256
#define SCAN_EPT 8
#define SCAN_CHUNK (SCAN_TPB * SCAN_EPT)  // 2048

#define ROWW 8   // uint words per bf16 row (16 channels x 2B = 32B)

// ---- workspace layout (bytes) ----
// offsets doubles as the count buffer (scan runs in-place).
#define WS_OFFSETS 0
#define WS_VR      ((TOTVOX + 4) * 4)                     //  7,077,904
#define WS_IDS     (WS_VR + TOTPTS * 4)                   // 11,993,104
#define WS_ROWS    (WS_IDS + TOTPTS * 4 + 16)             // 16,908,320 (32B aligned)
#define WS_SUMS    (WS_ROWS + (size_t)TOTPTS * ROWW * 4)  // 56,229,920
#define WS_NEEDED  ((size_t)(WS_SUMS + 4096))             // ~56.2 MB (< proven 90.6 MB budget)

// bf16 round-to-nearest-even (inputs finite)
__device__ __forceinline__ unsigned bf16_rtne(float f) {
    unsigned u = __float_as_uint(f);
    return (u + 0x7FFFu + ((u >> 16) & 1u)) >> 16;
}
__device__ __forceinline__ unsigned pack2(float lo, float hi) {
    return bf16_rtne(lo) | (bf16_rtne(hi) << 16);
}

// ============================== fast path ==============================

// Fused: per-point voxel id + histogram + POINT-ORDER bf16 row packing.
// 4 points/thread, float4 loads. The rows write is fully coalesced (point
// order, every 64B line completely dirtied) and overlaps the atomic latency
// this kernel is bound by. The atomic's return value is the point's rank,
// packed as (voxel << 10) | rank. OOB marker: 0xFFFFFFFF.
__global__ void k_hist_pack(const float* __restrict__ coords,   // [B,3,NPTS]
                            const float* __restrict__ attrs,    // [B,C,NPTS]
                            const float* __restrict__ origin,   // [B,3]
                            unsigned*    __restrict__ vr,       // [TOTPTS] packed
                            unsigned*    __restrict__ rows,     // [TOTPTS,8] words, point order
                            unsigned*    __restrict__ cnt)      // [TOTVOX] (= offsets buf)
{
    int t = blockIdx.x * blockDim.x + threadIdx.x;
    if (t >= TOTPTS / 4) return;
    int pid = t * 4;
    int b = pid / NPTS;          // NPTS % 4 == 0 -> all 4 points same batch
    int n = pid - b * NPTS;

    const float* cb = coords + (size_t)b * 3 * NPTS;
    float4 X = *(const float4*)(cb + n);
    float4 Y = *(const float4*)(cb + NPTS + n);
    float4 Z = *(const float4*)(cb + 2 * NPTS + n);
    float ox = origin[b * 3 + 0];
    float oy = origin[b * 3 + 1];
    float oz = origin[b * 3 + 2];

    // Pack 4 points' 16 channels to bf16 rows (point order, coalesced).
    const float* ab = attrs + (size_t)b * CHANS * NPTS + n;
    unsigned w[4][ROWW];
    #pragma unroll
    for (int c = 0; c < CHANS; c += 2) {
        float4 a0 = *(const float4*)(ab + (size_t)c * NPTS);
        float4 a1 = *(const float4*)(ab + (size_t)(c + 1) * NPTS);
        w[0][c >> 1] = pack2(a0.x, a1.x);
        w[1][c >> 1] = pack2(a0.y, a1.y);
        w[2][c >> 1] = pack2(a0.z, a1.z);
        w[3][c >> 1] = pack2(a0.w, a1.w);
    }
    #pragma unroll
    for (int k = 0; k < 4; ++k) {
        uint4* dst = (uint4*)(rows + (size_t)(pid + k) * ROWW);
        dst[0] = uint4{w[k][0], w[k][1], w[k][2], w[k][3]};
        dst[1] = uint4{w[k][4], w[k][5], w[k][6], w[k][7]};
    }

    float xs[4] = {X.x, X.y, X.z, X.w};
    float ys[4] = {Y.x, Y.y, Y.z, Y.w};
    float zs[4] = {Z.x, Z.y, Z.z, Z.w};
    unsigned ps[4];
    #pragma unroll
    for (int k = 0; k < 4; ++k) {
        // IEEE f32 division + floorf: must match numpy reference binning exactly.
        int ix = (int)floorf((xs[k] - ox) / VOXEL_SIZE);
        int iy = (int)floorf((ys[k] - oy) / VOXEL_SIZE);
        int iz = (int)floorf((zs[k] - oz) / VOXEL_SIZE);
        unsigned p = 0xFFFFFFFFu;
        if ((unsigned)ix < GRID_W && (unsigned)iy < GRID_L && (unsigned)iz < GRID_H) {
            int v = b * NVOX + ix * (GRID_L * GRID_H) + iy * GRID_H + iz;
            unsigned r = atomicAdd(&cnt[v], 1u);
            p = ((unsigned)v << 10) | (r & 1023u);
        }
        ps[k] = p;
    }
    *(uint4*)(vr + pid) = uint4{ps[0], ps[1], ps[2], ps[3]};
}

// Scan level 1, IN-PLACE on the count buffer: per-2048-chunk exclusive
// partials + chunk totals. Also emits the occupancy output plane.
__global__ void k_scan1(unsigned* __restrict__ offsets,   // counts in, partial offsets out
                        unsigned* __restrict__ sums,
                        float*    __restrict__ occ)       // [TOTVOX] in d_out
{
    __shared__ unsigned s[SCAN_TPB];
    int t = threadIdx.x;
    int base = blockIdx.x * SCAN_CHUNK + t * SCAN_EPT;

    uint4 a = ((const uint4*)(offsets + base))[0];
    uint4 c = ((const uint4*)(offsets + base))[1];
    unsigned e[SCAN_EPT] = {a.x, a.y, a.z, a.w, c.x, c.y, c.z, c.w};

    float4 oc0, oc1;
    oc0.x = (e[0] >= MIN_PTS) ? 1.f : 0.f;  oc0.y = (e[1] >= MIN_PTS) ? 1.f : 0.f;
    oc0.z = (e[2] >= MIN_PTS) ? 1.f : 0.f;  oc0.w = (e[3] >= MIN_PTS) ? 1.f : 0.f;
    oc1.x = (e[4] >= MIN_PTS) ? 1.f : 0.f;  oc1.y = (e[5] >= MIN_PTS) ? 1.f : 0.f;
    oc1.z = (e[6] >= MIN_PTS) ? 1.f : 0.f;  oc1.w = (e[7] >= MIN_PTS) ? 1.f : 0.f;
    ((float4*)(occ + base))[0] = oc0;
    ((float4*)(occ + base))[1] = oc1;

    unsigned tot = 0;
    #pragma unroll
    for (int k = 0; k < SCAN_EPT; ++k) { unsigned v = e[k]; e[k] = tot; tot += v; }

    s[t] = tot;
    __syncthreads();
    #pragma unroll
    for (int off = 1; off < SCAN_TPB; off <<= 1) {
        unsigned v = (t >= off) ? s[t - off] : 0u;
        __syncthreads();
        s[t] += v;
        __syncthreads();
    }
    unsigned prefix = s[t] - tot;   // exclusive within chunk
    #pragma unroll
    for (int k = 0; k < SCAN_EPT; ++k) e[k] += prefix;

    ((uint4*)(offsets + base))[0] = uint4{e[0], e[1], e[2], e[3]};
    ((uint4*)(offsets + base))[1] = uint4{e[4], e[5], e[6], e[7]};

    if (t == SCAN_TPB - 1) sums[blockIdx.x] = s[t];
}

// Scan level 2: exclusive scan of the 864 chunk sums (single block).
// Consumers add sums[v >> 11] themselves. sums[SCAN_BLKS] = grand total.
__global__ void k_scan2(unsigned* __restrict__ sums) {
    __shared__ unsigned s[1024];
    int t = threadIdx.x;
    unsigned my = (t < SCAN_BLKS) ? sums[t] : 0u;
    s[t] = my;
    __syncthreads();
    #pragma unroll
    for (int off = 1; off < 1024; off <<= 1) {
        unsigned v = (t >= off) ? s[t - off] : 0u;
        __syncthreads();
        s[t] += v;
        __syncthreads();
    }
    if (t < SCAN_BLKS) sums[t] = s[t] - my;          // exclusive
    if (t == SCAN_BLKS - 1) sums[SCAN_BLKS] = s[t];  // grand total sentinel
}

// Scatter point-ids into voxel segments. The random 4 B writes land in a
// 4.9 MB array -> fully absorbed by the 32 MB aggregate L2. No atomics.
__global__ void k_scatter_ids4(const unsigned* __restrict__ vr,      // [TOTPTS] packed
                               const unsigned* __restrict__ offsets, // [TOTVOX]
                               const unsigned* __restrict__ sums,    // [SCAN_BLKS+1]
                               int*            __restrict__ ids)     // [TOTPTS]
{
    int t = blockIdx.x * blockDim.x + threadIdx.x;
    if (t >= TOTPTS / 4) return;
    int pid = t * 4;
    uint4 P = *(const uint4*)(vr + pid);
    unsigned ps[4] = {P.x, P.y, P.z, P.w};
    #pragma unroll
    for (int k = 0; k < 4; ++k) {
        if (ps[k] != 0xFFFFFFFFu) {
            unsigned v = ps[k] >> 10;
            unsigned pos = offsets[v] + sums[v >> 11] + (ps[k] & 1023u);
            ids[pos] = pid + k;
        }
    }
}

// Gather + finalize: ONE thread per 4 adjacent voxels, all 16 channels.
// Sequential ids reads; random 32 B row reads (each 64 B line touched <=2x,
// single-use -> no cache-residency requirement); 16 coalesced float4 stores.
__global__ void k_gather_ind4(const unsigned* __restrict__ rows,    // [TOTPTS,8] point order
                              const int*      __restrict__ ids,     // [TOTPTS]
                              const unsigned* __restrict__ offsets, // [TOTVOX+4]
                              const unsigned* __restrict__ sums,    // [SCAN_BLKS+1]
                              float*          __restrict__ data)    // [B,C,NVOX]
{
    int g = blockIdx.x * blockDim.x + threadIdx.x;
    if (g >= TOTVOX / 4) return;
    int vox0 = g * 4;

    // vox0 % 4 == 0 and chunk size 2048 % 4 == 0 -> vox0..vox0+3 same chunk.
    uint4 O = *(const uint4*)(offsets + vox0);
    unsigned base = sums[vox0 >> 11];
    unsigned s[5];
    s[0] = O.x + base; s[1] = O.y + base; s[2] = O.z + base; s[3] = O.w + base;
    s[4] = offsets[vox0 + 4] + sums[(vox0 + 4) >> 11];  // sentinels cover end

    float m[4][CHANS];
    #pragma unroll
    for (int q = 0; q < 4; ++q) {
        unsigned k = s[q + 1] - s[q];
        unsigned s0 = s[q];
        if (k >= MIN_PTS) {
            const float ninf = -__builtin_inff();
            #pragma unroll
            for (int c = 0; c < CHANS; ++c) m[q][c] = ninf;
            unsigned j = 0;
            for (; j + 2 <= k; j += 2) {           // unroll x2 for MLP
                int p0 = ids[s0 + j];
                int p1 = ids[s0 + j + 1];
                const uint4* r0p = (const uint4*)(rows + (size_t)p0 * ROWW);
                const uint4* r1p = (const uint4*)(rows + (size_t)p1 * ROWW);
                uint4 l0 = r0p[0], h0 = r0p[1];
                uint4 l1 = r1p[0], h1 = r1p[1];
                unsigned wa[8] = {l0.x, l0.y, l0.z, l0.w, h0.x, h0.y, h0.z, h0.w};
                unsigned wb[8] = {l1.x, l1.y, l1.z, l1.w, h1.x, h1.y, h1.z, h1.w};
                #pragma unroll
                for (int h = 0; h < 8; ++h) {
                    m[q][2 * h]     = fmaxf(m[q][2 * h],
                                        fmaxf(__uint_as_float(wa[h] << 16),
                                              __uint_as_float(wb[h] << 16)));
                    m[q][2 * h + 1] = fmaxf(m[q][2 * h + 1],
                                        fmaxf(__uint_as_float(wa[h] & 0xFFFF0000u),
                                              __uint_as_float(wb[h] & 0xFFFF0000u)));
                }
            }
            if (j < k) {
                int p0 = ids[s0 + j];
                const uint4* r0p = (const uint4*)(rows + (size_t)p0 * ROWW);
                uint4 l0 = r0p[0], h0 = r0p[1];
                unsigned wa[8] = {l0.x, l0.y, l0.z, l0.w, h0.x, h0.y, h0.z, h0.w};
                #pragma unroll
                for (int h = 0; h < 8; ++h) {
                    m[q][2 * h]     = fmaxf(m[q][2 * h], __uint_as_float(wa[h] << 16));
                    m[q][2 * h + 1] = fmaxf(m[q][2 * h + 1],
                                            __uint_as_float(wa[h] & 0xFFFF0000u));
                }
            }
            #pragma unroll
            for (int c = 0; c < CHANS; ++c) if (!isfinite(m[q][c])) m[q][c] = 0.f;
        } else {
            #pragma unroll
            for (int c = 0; c < CHANS; ++c) m[q][c] = 0.f;
        }
    }

    int b = vox0 / NVOX;                 // NVOX % 4 == 0
    int v0 = vox0 - b * NVOX;
    float* db = data + (size_t)b * CHANS * NVOX + v0;
    #pragma unroll
    for (int c = 0; c < CHANS; ++c) {
        *(float4*)(db + (size_t)c * NVOX) = float4{m[0][c], m[1][c], m[2][c], m[3][c]};
    }
}

// ============================== fallback path (round-1) ==============================

__device__ __forceinline__ unsigned flip_f32(float f) {
    unsigned u = __float_as_uint(f);
    unsigned mask = (unsigned)(-(int)(u >> 31)) | 0x80000000u;
    return u ^ mask;
}
__device__ __forceinline__ float unflip_f32(unsigned u) {
    unsigned mask = ((u >> 31) - 1u) | 0x80000000u;
    return __uint_as_float(u ^ mask);
}
#define FLIP_NEG_INF 0x007FFFFFu

__global__ void pv_init(uint4* __restrict__ out) {
    const int DATA4 = BATCH * CHANS * NVOX / 4;
    const int TOT4  = BATCH * (CHANS + 1) * NVOX / 4;
    int i = blockIdx.x * blockDim.x + threadIdx.x;
    if (i < TOT4) {
        unsigned val = (i < DATA4) ? FLIP_NEG_INF : 0u;
        out[i] = uint4{val, val, val, val};
    }
}

__global__ void pv_scatter(const float* __restrict__ coords,
                           const float* __restrict__ attrs,
                           const float* __restrict__ origin,
                           unsigned*    __restrict__ data_u,
                           unsigned*    __restrict__ cnt)
{
    int id = blockIdx.x * blockDim.x + threadIdx.x;
    if (id >= TOTPTS) return;
    int b = id / NPTS;
    int n = id - b * NPTS;
    const float* cb = coords + (size_t)b * 3 * NPTS;
    float x = cb[n], y = cb[NPTS + n], z = cb[2 * NPTS + n];
    float ox = origin[b * 3 + 0], oy = origin[b * 3 + 1], oz = origin[b * 3 + 2];
    int ix = (int)floorf((x - ox) / VOXEL_SIZE);
    int iy = (int)floorf((y - oy) / VOXEL_SIZE);
    int iz = (int)floorf((z - oz) / VOXEL_SIZE);
    if ((unsigned)ix < GRID_W && (unsigned)iy < GRID_L && (unsigned)iz < GRID_H) {
        int flat = ix * (GRID_L * GRID_H) + iy * GRID_H + iz;
        atomicAdd(&cnt[b * NVOX + flat], 1u);
        const float* ab = attrs + (size_t)b * CHANS * NPTS + n;
        unsigned*    db = data_u + (size_t)b * CHANS * NVOX + flat;
        #pragma unroll
        for (int c = 0; c < CHANS; ++c)
            atomicMax(&db[(size_t)c * NVOX], flip_f32(ab[(size_t)c * NPTS]));
    }
}

__global__ void pv_finalize(unsigned* __restrict__ data_u,
                            unsigned* __restrict__ cnt_u)
{
    int id = blockIdx.x * blockDim.x + threadIdx.x;
    if (id >= TOTVOX) return;
    int b = id / NVOX;
    int v = id - b * NVOX;
    unsigned cnt = cnt_u[id];
    bool occ = (cnt >= MIN_PTS);
    ((float*)cnt_u)[id] = occ ? 1.0f : 0.0f;
    unsigned* db = data_u + (size_t)b * CHANS * NVOX + v;
    #pragma unroll
    for (int c = 0; c < CHANS; ++c) {
        float f = unflip_f32(db[(size_t)c * NVOX]);
        ((float*)db)[(size_t)c * NVOX] = (occ && isfinite(f)) ? f : 0.0f;
    }
}

// ============================== launch ==============================

extern "C" void kernel_launch(void* const* d_in, const int* in_sizes, int n_in,
                              void* d_out, int out_size, void* d_ws, size_t ws_size,
                              hipStream_t stream) {
    const float* coords = (const float*)d_in[0];  // [4,3,480,640]
    const float* attrs  = (const float*)d_in[1];  // [4,16,480,640]
    const float* origin = (const float*)d_in[2];  // [4,3]

    float* out = (float*)d_out;
    float* data = out;                                          // [B,C,NVOX]
    float* occ  = out + (size_t)BATCH * CHANS * NVOX;           // [B,NVOX]

    if (ws_size >= WS_NEEDED) {
        char* ws = (char*)d_ws;
        unsigned* offsets = (unsigned*)(ws + WS_OFFSETS);  // counts -> offsets (in-place)
        unsigned* vr      = (unsigned*)(ws + WS_VR);
        int*      ids     = (int*)(ws + WS_IDS);
        unsigned* rows    = (unsigned*)(ws + WS_ROWS);
        unsigned* sums    = (unsigned*)(ws + WS_SUMS);

        // zero counts + the 4 sentinel words past the end
        hipMemsetAsync(offsets, 0, (size_t)(TOTVOX + 4) * 4, stream);
        k_hist_pack<<<(TOTPTS / 4 + 255) / 256, 256, 0, stream>>>(coords, attrs, origin,
                                                                  vr, rows, offsets);
        k_scan1<<<SCAN_BLKS, SCAN_TPB, 0, stream>>>(offsets, sums, occ);
        k_scan2<<<1, 1024, 0, stream>>>(sums);
        k_scatter_ids4<<<(TOTPTS / 4 + 255) / 256, 256, 0, stream>>>(vr, offsets, sums, ids);
        k_gather_ind4<<<(TOTVOX / 4 + 255) / 256, 256, 0, stream>>>(rows, ids, offsets, sums, data);
    } else {
        unsigned* data_u = (unsigned*)data;
        unsigned* cnt    = (unsigned*)occ;
        const int TOT4 = BATCH * (CHANS + 1) * NVOX / 4;
        pv_init<<<(TOT4 + 255) / 256, 256, 0, stream>>>((uint4*)d_out);
        pv_scatter<<<(TOTPTS + 255) / 256, 256, 0, stream>>>(coords, attrs, origin, data_u, cnt);
        pv_finalize<<<(TOTVOX + 255) / 256, 256, 0, stream>>>(data_u, cnt);
    }
}

// Round 9
// 300.421 us; speedup vs baseline: 1.3037x; 1.0431x over previous
//
#include <hip/hip_runtime.h>
#include <cstdint>
#include <math.h>

// Problem constants (from reference)
#define GRID_W 96
#define GRID_L 96
#define GRID_H 48
#define NVOX (GRID_W * GRID_L * GRID_H)   // 442368
#define VOXEL_SIZE 0.05f
#define MIN_PTS 10
#define BATCH 4
#define CHANS 16
#define NPTS (480 * 640)                  // 307200 points per batch
#define TOTPTS (BATCH * NPTS)             // 1228800
#define TOTVOX (BATCH * NVOX)             // 1769472

// Scan geometry: 864 blocks x 256 threads x 8 elems = 1769472 exactly.
#define SCAN_BLKS 864
#define SCAN_TPB 256
#define SCAN_EPT 8
#define SCAN_CHUNK (SCAN_TPB * SCAN_EPT)  // 2048

#define ROWW 8   // uint words per bf16 row (16 channels x 2B = 32B)

// Native vector types for __builtin_nontemporal_store (HIP_vector_type is rejected).
typedef unsigned nt_uint4 __attribute__((ext_vector_type(4)));
typedef float    nt_float4 __attribute__((ext_vector_type(4)));
typedef float    nt_float2 __attribute__((ext_vector_type(2)));

// ---- workspace layout (bytes) ----
// offsets doubles as the count buffer (scan runs in-place).
#define WS_OFFSETS 0
#define WS_VR      ((TOTVOX + 4) * 4)                     //  7,077,904
#define WS_IDS     (WS_VR + TOTPTS * 4)                   // 11,993,104
#define WS_ROWS    (WS_IDS + TOTPTS * 4 + 16)             // 16,908,320 (32B aligned)
#define WS_SUMS    (WS_ROWS + (size_t)TOTPTS * ROWW * 4)  // 56,229,920
#define WS_NEEDED  ((size_t)(WS_SUMS + 4096))             // ~56.2 MB (< proven 90.6 MB budget)

// bf16 round-to-nearest-even (inputs finite)
__device__ __forceinline__ unsigned bf16_rtne(float f) {
    unsigned u = __float_as_uint(f);
    return (u + 0x7FFFu + ((u >> 16) & 1u)) >> 16;
}
__device__ __forceinline__ unsigned pack2(float lo, float hi) {
    return bf16_rtne(lo) | (bf16_rtne(hi) << 16);
}

// ============================== fast path ==============================

// Fused: per-point voxel id + histogram + POINT-ORDER bf16 row packing.
// ONE point per thread (4800 blocks -> max wave parallelism for the
// returning-atomic latency). rows/vr writes are nontemporal so the
// streaming traffic does not evict the hot ~430 KB cnt working set from L2.
__global__ void k_hist_pack(const float* __restrict__ coords,   // [B,3,NPTS]
                            const float* __restrict__ attrs,    // [B,C,NPTS]
                            const float* __restrict__ origin,   // [B,3]
                            unsigned*    __restrict__ vr,       // [TOTPTS] packed
                            unsigned*    __restrict__ rows,     // [TOTPTS,8] words, point order
                            unsigned*    __restrict__ cnt)      // [TOTVOX] (= offsets buf)
{
    int pid = blockIdx.x * blockDim.x + threadIdx.x;
    if (pid >= TOTPTS) return;
    int b = pid / NPTS;
    int n = pid - b * NPTS;

    const float* cb = coords + (size_t)b * 3 * NPTS;
    float x = cb[n];
    float y = cb[NPTS + n];
    float z = cb[2 * NPTS + n];
    float ox = origin[b * 3 + 0];
    float oy = origin[b * 3 + 1];
    float oz = origin[b * 3 + 2];

    // Pack this point's 16 channels to a 32 B bf16 row (coalesced loads:
    // lane i reads plane[c] at n+i -> 256 B/wave per instruction).
    const float* ab = attrs + (size_t)b * CHANS * NPTS + n;
    unsigned w[ROWW];
    #pragma unroll
    for (int c = 0; c < CHANS; c += 2) {
        float a0 = ab[(size_t)c * NPTS];
        float a1 = ab[(size_t)(c + 1) * NPTS];
        w[c >> 1] = pack2(a0, a1);
    }
    nt_uint4* dst = (nt_uint4*)(rows + (size_t)pid * ROWW);
    nt_uint4 lo = {w[0], w[1], w[2], w[3]};
    nt_uint4 hi = {w[4], w[5], w[6], w[7]};
    __builtin_nontemporal_store(lo, dst);
    __builtin_nontemporal_store(hi, dst + 1);

    // IEEE f32 division + floorf: must match numpy reference binning exactly.
    int ix = (int)floorf((x - ox) / VOXEL_SIZE);
    int iy = (int)floorf((y - oy) / VOXEL_SIZE);
    int iz = (int)floorf((z - oz) / VOXEL_SIZE);
    unsigned p = 0xFFFFFFFFu;
    if ((unsigned)ix < GRID_W && (unsigned)iy < GRID_L && (unsigned)iz < GRID_H) {
        int v = b * NVOX + ix * (GRID_L * GRID_H) + iy * GRID_H + iz;
        unsigned r = atomicAdd(&cnt[v], 1u);
        p = ((unsigned)v << 10) | (r & 1023u);
    }
    __builtin_nontemporal_store(p, vr + pid);
}

// Scan level 1, IN-PLACE on the count buffer: per-2048-chunk exclusive
// partials + chunk totals. Also emits the occupancy output plane.
__global__ void k_scan1(unsigned* __restrict__ offsets,   // counts in, partial offsets out
                        unsigned* __restrict__ sums,
                        float*    __restrict__ occ)       // [TOTVOX] in d_out
{
    __shared__ unsigned s[SCAN_TPB];
    int t = threadIdx.x;
    int base = blockIdx.x * SCAN_CHUNK + t * SCAN_EPT;

    uint4 a = ((const uint4*)(offsets + base))[0];
    uint4 c = ((const uint4*)(offsets + base))[1];
    unsigned e[SCAN_EPT] = {a.x, a.y, a.z, a.w, c.x, c.y, c.z, c.w};

    nt_float4 oc0, oc1;
    oc0.x = (e[0] >= MIN_PTS) ? 1.f : 0.f;  oc0.y = (e[1] >= MIN_PTS) ? 1.f : 0.f;
    oc0.z = (e[2] >= MIN_PTS) ? 1.f : 0.f;  oc0.w = (e[3] >= MIN_PTS) ? 1.f : 0.f;
    oc1.x = (e[4] >= MIN_PTS) ? 1.f : 0.f;  oc1.y = (e[5] >= MIN_PTS) ? 1.f : 0.f;
    oc1.z = (e[6] >= MIN_PTS) ? 1.f : 0.f;  oc1.w = (e[7] >= MIN_PTS) ? 1.f : 0.f;
    __builtin_nontemporal_store(oc0, ((nt_float4*)(occ + base)));
    __builtin_nontemporal_store(oc1, ((nt_float4*)(occ + base)) + 1);

    unsigned tot = 0;
    #pragma unroll
    for (int k = 0; k < SCAN_EPT; ++k) { unsigned v = e[k]; e[k] = tot; tot += v; }

    s[t] = tot;
    __syncthreads();
    #pragma unroll
    for (int off = 1; off < SCAN_TPB; off <<= 1) {
        unsigned v = (t >= off) ? s[t - off] : 0u;
        __syncthreads();
        s[t] += v;
        __syncthreads();
    }
    unsigned prefix = s[t] - tot;   // exclusive within chunk
    #pragma unroll
    for (int k = 0; k < SCAN_EPT; ++k) e[k] += prefix;

    ((uint4*)(offsets + base))[0] = uint4{e[0], e[1], e[2], e[3]};
    ((uint4*)(offsets + base))[1] = uint4{e[4], e[5], e[6], e[7]};

    if (t == SCAN_TPB - 1) sums[blockIdx.x] = s[t];
}

// Scan level 2: exclusive scan of the 864 chunk sums (single block).
// Consumers add sums[v >> 11] themselves. sums[SCAN_BLKS] = grand total.
__global__ void k_scan2(unsigned* __restrict__ sums) {
    __shared__ unsigned s[1024];
    int t = threadIdx.x;
    unsigned my = (t < SCAN_BLKS) ? sums[t] : 0u;
    s[t] = my;
    __syncthreads();
    #pragma unroll
    for (int off = 1; off < 1024; off <<= 1) {
        unsigned v = (t >= off) ? s[t - off] : 0u;
        __syncthreads();
        s[t] += v;
        __syncthreads();
    }
    if (t < SCAN_BLKS) sums[t] = s[t] - my;          // exclusive
    if (t == SCAN_BLKS - 1) sums[SCAN_BLKS] = s[t];  // grand total sentinel
}

// Scatter point-ids into voxel segments. The random 4 B writes land in a
// 4.9 MB array -> fully absorbed by the 32 MB aggregate L2. No atomics.
__global__ void k_scatter_ids4(const unsigned* __restrict__ vr,      // [TOTPTS] packed
                               const unsigned* __restrict__ offsets, // [TOTVOX]
                               const unsigned* __restrict__ sums,    // [SCAN_BLKS+1]
                               int*            __restrict__ ids)     // [TOTPTS]
{
    int t = blockIdx.x * blockDim.x + threadIdx.x;
    if (t >= TOTPTS / 4) return;
    int pid = t * 4;
    uint4 P = *(const uint4*)(vr + pid);
    unsigned ps[4] = {P.x, P.y, P.z, P.w};
    #pragma unroll
    for (int k = 0; k < 4; ++k) {
        if (ps[k] != 0xFFFFFFFFu) {
            unsigned v = ps[k] >> 10;
            unsigned pos = offsets[v] + sums[v >> 11] + (ps[k] & 1023u);
            ids[pos] = pid + k;
        }
    }
}

// Gather + finalize: ONE thread per 2 adjacent voxels, all 16 channels
// (lower VGPR pressure than 4-voxel -> more resident waves to hide the
// random 32 B row-read latency). Sequential ids reads; j-loop unrolled x2
// (4 row-loads outstanding). Nontemporal float2 output stores (single-use
// 113 MB stream, keeps ids/rows lines in L2).
__global__ void k_gather_ind2(const unsigned* __restrict__ rows,    // [TOTPTS,8] point order
                              const int*      __restrict__ ids,     // [TOTPTS]
                              const unsigned* __restrict__ offsets, // [TOTVOX+4]
                              const unsigned* __restrict__ sums,    // [SCAN_BLKS+1]
                              float*          __restrict__ data)    // [B,C,NVOX]
{
    int g = blockIdx.x * blockDim.x + threadIdx.x;
    if (g >= TOTVOX / 2) return;
    int vox0 = g * 2;

    // vox0 % 2 == 0 and chunk size 2048 % 2 == 0 -> vox0, vox0+1 same chunk.
    uint2 O = *(const uint2*)(offsets + vox0);
    unsigned base = sums[vox0 >> 11];
    unsigned s[3];
    s[0] = O.x + base;
    s[1] = O.y + base;
    s[2] = offsets[vox0 + 2] + sums[(vox0 + 2) >> 11];  // sentinels cover end

    float m[2][CHANS];
    #pragma unroll
    for (int q = 0; q < 2; ++q) {
        unsigned k = s[q + 1] - s[q];
        unsigned s0 = s[q];
        if (k >= MIN_PTS) {
            const float ninf = -__builtin_inff();
            #pragma unroll
            for (int c = 0; c < CHANS; ++c) m[q][c] = ninf;
            unsigned j = 0;
            for (; j + 2 <= k; j += 2) {           // unroll x2 for MLP
                int p0 = ids[s0 + j];
                int p1 = ids[s0 + j + 1];
                const uint4* r0p = (const uint4*)(rows + (size_t)p0 * ROWW);
                const uint4* r1p = (const uint4*)(rows + (size_t)p1 * ROWW);
                uint4 l0 = r0p[0], h0 = r0p[1];
                uint4 l1 = r1p[0], h1 = r1p[1];
                unsigned wa[8] = {l0.x, l0.y, l0.z, l0.w, h0.x, h0.y, h0.z, h0.w};
                unsigned wb[8] = {l1.x, l1.y, l1.z, l1.w, h1.x, h1.y, h1.z, h1.w};
                #pragma unroll
                for (int h = 0; h < 8; ++h) {
                    m[q][2 * h]     = fmaxf(m[q][2 * h],
                                        fmaxf(__uint_as_float(wa[h] << 16),
                                              __uint_as_float(wb[h] << 16)));
                    m[q][2 * h + 1] = fmaxf(m[q][2 * h + 1],
                                        fmaxf(__uint_as_float(wa[h] & 0xFFFF0000u),
                                              __uint_as_float(wb[h] & 0xFFFF0000u)));
                }
            }
            if (j < k) {
                int p0 = ids[s0 + j];
                const uint4* r0p = (const uint4*)(rows + (size_t)p0 * ROWW);
                uint4 l0 = r0p[0], h0 = r0p[1];
                unsigned wa[8] = {l0.x, l0.y, l0.z, l0.w, h0.x, h0.y, h0.z, h0.w};
                #pragma unroll
                for (int h = 0; h < 8; ++h) {
                    m[q][2 * h]     = fmaxf(m[q][2 * h], __uint_as_float(wa[h] << 16));
                    m[q][2 * h + 1] = fmaxf(m[q][2 * h + 1],
                                            __uint_as_float(wa[h] & 0xFFFF0000u));
                }
            }
            #pragma unroll
            for (int c = 0; c < CHANS; ++c) if (!isfinite(m[q][c])) m[q][c] = 0.f;
        } else {
            #pragma unroll
            for (int c = 0; c < CHANS; ++c) m[q][c] = 0.f;
        }
    }

    int b = vox0 / NVOX;                 // NVOX % 2 == 0
    int v0 = vox0 - b * NVOX;
    float* db = data + (size_t)b * CHANS * NVOX + v0;
    #pragma unroll
    for (int c = 0; c < CHANS; ++c) {
        nt_float2 o = {m[0][c], m[1][c]};
        __builtin_nontemporal_store(o, (nt_float2*)(db + (size_t)c * NVOX));
    }
}

// ============================== fallback path (round-1) ==============================

__device__ __forceinline__ unsigned flip_f32(float f) {
    unsigned u = __float_as_uint(f);
    unsigned mask = (unsigned)(-(int)(u >> 31)) | 0x80000000u;
    return u ^ mask;
}
__device__ __forceinline__ float unflip_f32(unsigned u) {
    unsigned mask = ((u >> 31) - 1u) | 0x80000000u;
    return __uint_as_float(u ^ mask);
}
#define FLIP_NEG_INF 0x007FFFFFu

__global__ void pv_init(uint4* __restrict__ out) {
    const int DATA4 = BATCH * CHANS * NVOX / 4;
    const int TOT4  = BATCH * (CHANS + 1) * NVOX / 4;
    int i = blockIdx.x * blockDim.x + threadIdx.x;
    if (i < TOT4) {
        unsigned val = (i < DATA4) ? FLIP_NEG_INF : 0u;
        out[i] = uint4{val, val, val, val};
    }
}

__global__ void pv_scatter(const float* __restrict__ coords,
                           const float* __restrict__ attrs,
                           const float* __restrict__ origin,
                           unsigned*    __restrict__ data_u,
                           unsigned*    __restrict__ cnt)
{
    int id = blockIdx.x * blockDim.x + threadIdx.x;
    if (id >= TOTPTS) return;
    int b = id / NPTS;
    int n = id - b * NPTS;
    const float* cb = coords + (size_t)b * 3 * NPTS;
    float x = cb[n], y = cb[NPTS + n], z = cb[2 * NPTS + n];
    float ox = origin[b * 3 + 0], oy = origin[b * 3 + 1], oz = origin[b * 3 + 2];
    int ix = (int)floorf((x - ox) / VOXEL_SIZE);
    int iy = (int)floorf((y - oy) / VOXEL_SIZE);
    int iz = (int)floorf((z - oz) / VOXEL_SIZE);
    if ((unsigned)ix < GRID_W && (unsigned)iy < GRID_L && (unsigned)iz < GRID_H) {
        int flat = ix * (GRID_L * GRID_H) + iy * GRID_H + iz;
        atomicAdd(&cnt[b * NVOX + flat], 1u);
        const float* ab = attrs + (size_t)b * CHANS * NPTS + n;
        unsigned*    db = data_u + (size_t)b * CHANS * NVOX + flat;
        #pragma unroll
        for (int c = 0; c < CHANS; ++c)
            atomicMax(&db[(size_t)c * NVOX], flip_f32(ab[(size_t)c * NPTS]));
    }
}

__global__ void pv_finalize(unsigned* __restrict__ data_u,
                            unsigned* __restrict__ cnt_u)
{
    int id = blockIdx.x * blockDim.x + threadIdx.x;
    if (id >= TOTVOX) return;
    int b = id / NVOX;
    int v = id - b * NVOX;
    unsigned cnt = cnt_u[id];
    bool occ = (cnt >= MIN_PTS);
    ((float*)cnt_u)[id] = occ ? 1.0f : 0.0f;
    unsigned* db = data_u + (size_t)b * CHANS * NVOX + v;
    #pragma unroll
    for (int c = 0; c < CHANS; ++c) {
        float f = unflip_f32(db[(size_t)c * NVOX]);
        ((float*)db)[(size_t)c * NVOX] = (occ && isfinite(f)) ? f : 0.0f;
    }
}

// ============================== launch ==============================

extern "C" void kernel_launch(void* const* d_in, const int* in_sizes, int n_in,
                              void* d_out, int out_size, void* d_ws, size_t ws_size,
                              hipStream_t stream) {
    const float* coords = (const float*)d_in[0];  // [4,3,480,640]
    const float* attrs  = (const float*)d_in[1];  // [4,16,480,640]
    const float* origin = (const float*)d_in[2];  // [4,3]

    float* out = (float*)d_out;
    float* data = out;                                          // [B,C,NVOX]
    float* occ  = out + (size_t)BATCH * CHANS * NVOX;           // [B,NVOX]

    if (ws_size >= WS_NEEDED) {
        char* ws = (char*)d_ws;
        unsigned* offsets = (unsigned*)(ws + WS_OFFSETS);  // counts -> offsets (in-place)
        unsigned* vr      = (unsigned*)(ws + WS_VR);
        int*      ids     = (int*)(ws + WS_IDS);
        unsigned* rows    = (unsigned*)(ws + WS_ROWS);
        unsigned* sums    = (unsigned*)(ws + WS_SUMS);

        // zero counts + the 4 sentinel words past the end
        (void)hipMemsetAsync(offsets, 0, (size_t)(TOTVOX + 4) * 4, stream);
        k_hist_pack<<<(TOTPTS + 255) / 256, 256, 0, stream>>>(coords, attrs, origin,
                                                              vr, rows, offsets);
        k_scan1<<<SCAN_BLKS, SCAN_TPB, 0, stream>>>(offsets, sums, occ);
        k_scan2<<<1, 1024, 0, stream>>>(sums);
        k_scatter_ids4<<<(TOTPTS / 4 + 255) / 256, 256, 0, stream>>>(vr, offsets, sums, ids);
        k_gather_ind2<<<(TOTVOX / 2 + 255) / 256, 256, 0, stream>>>(rows, ids, offsets, sums, data);
    } else {
        unsigned* data_u = (unsigned*)data;
        unsigned* cnt    = (unsigned*)occ;
        const int TOT4 = BATCH * (CHANS + 1) * NVOX / 4;
        pv_init<<<(TOT4 + 255) / 256, 256, 0, stream>>>((uint4*)d_out);
        pv_scatter<<<(TOTPTS + 255) / 256, 256, 0, stream>>>(coords, attrs, origin, data_u, cnt);
        pv_finalize<<<(TOTVOX + 255) / 256, 256, 0, stream>>>(data_u, cnt);
    }
}